// Round 11
// baseline (278.727 us; speedup 1.0000x reference)
//
#include <hip/hip_runtime.h>
#include <hip/hip_bf16.h>

typedef __bf16 bf16_t;
typedef __attribute__((ext_vector_type(8))) __bf16 bf16x8;
typedef __attribute__((ext_vector_type(4))) __bf16 bf16x4;
typedef __attribute__((ext_vector_type(4))) float f32x4;

static constexpr int Bn = 4, Tn = 4096, Cn = 1024, Hn = 16, CSn = 128, Dn = 64, NCn = 32;

#define DEVINL __device__ __forceinline__

DEVINL float wsum64(float v) {
  v += __shfl_xor(v, 32, 64);
  v += __shfl_xor(v, 16, 64);
  v += __shfl_xor(v, 8, 64);
  v += __shfl_xor(v, 4, 64);
  v += __shfl_xor(v, 2, 64);
  v += __shfl_xor(v, 1, 64);
  return v;
}

// fast erf-based GELU (A&S 7.1.26, |erf err| <= 1.5e-7, far below bf16 rounding)
DEVINL float gelu_f(float v) {
  float x = v * 0.70710678f;
  float ax = fabsf(x);
  float t = 1.f / (1.f + 0.3275911f * ax);
  float poly = t * (0.254829592f +
               t * (-0.284496736f +
               t * (1.421413741f +
               t * (-1.453152027f +
               t * 1.061405429f))));
  float e = __expf(-ax * ax);
  float erfax = 1.f - poly * e;
  float erfx = copysignf(erfax, x);
  return 0.5f * v * (1.f + erfx);
}

// direct global->LDS, 16B per lane; LDS dest is wave-uniform base + lane*16
DEVINL void gld16(const bf16_t* g, bf16_t* l) {
  __builtin_amdgcn_global_load_lds(
      (const __attribute__((address_space(1))) unsigned int*)(g),
      (__attribute__((address_space(3))) unsigned int*)(l), 16, 0, 0);
}

// ------------- x fp32 -> bf16 (contiguous) -------------------------------------
__global__ __launch_bounds__(256) void k_xbf(const float* __restrict__ in,
                                             bf16_t* __restrict__ out) {
  int i = blockIdx.x * 256 + threadIdx.x;  // one per 8 elements
  float4 a = *reinterpret_cast<const float4*>(in + (size_t)i * 8);
  float4 b = *reinterpret_cast<const float4*>(in + (size_t)i * 8 + 4);
  bf16x8 o = {(bf16_t)a.x, (bf16_t)a.y, (bf16_t)a.z, (bf16_t)a.w,
              (bf16_t)b.x, (bf16_t)b.y, (bf16_t)b.z, (bf16_t)b.w};
  *reinterpret_cast<bf16x8*>(out + (size_t)i * 8) = o;
}

// ------------- transpose fp32 (rows x cols) -> bf16 (cols x rows) --------------
__global__ void k_transpose(const float* __restrict__ in, bf16_t* __restrict__ out,
                            int rows, int cols) {
  __shared__ float tile[64][65];
  int c0 = blockIdx.x * 64, r0 = blockIdx.y * 64;
  int tx = threadIdx.x & 63, ty = threadIdx.x >> 6;
#pragma unroll
  for (int i = ty; i < 64; i += 4)
    tile[i][tx] = in[(size_t)(r0 + i) * cols + c0 + tx];
  __syncthreads();
#pragma unroll
  for (int i = ty; i < 64; i += 4)
    out[(size_t)(c0 + i) * rows + r0 + tx] = (bf16_t)tile[tx][i];
}

// ---------------- fused dual GEMM + sigmoid*mul + chunk cumsum ------------------
// Block tile 128(M) x 64(N) = one (b,chunk) x one head. BK=32, 2-phase dbuf.
__global__ __launch_bounds__(256, 3) void k_dualgemm_gm(
    const bf16_t* __restrict__ X, const bf16_t* __restrict__ Wtm,
    const bf16_t* __restrict__ Wtg, const float* __restrict__ bm,
    const float* __restrict__ bg, bf16_t* __restrict__ lcm,
    float* __restrict__ csum) {
  constexpr int K = Cn, N = Cn;
  constexpr int GP = 68;  // padded G-tile stride
  __shared__ __align__(16) bf16_t L[16384];
  __shared__ float tot[4][64];
  int tid = threadIdx.x;
  int Lb = blockIdx.x;            // 0..2047
  int xcd = Lb & 7, jj = Lb >> 3; // jj 0..255
  int nb = jj & 15, mb = xcd + 8 * (jj >> 4);
  int m0 = mb * 128, n0 = nb * 64;
  int wave = tid >> 6, lane = tid & 63;
  int wm = wave >> 1, wn = wave & 1;
  int lr = lane & 15, lk = lane >> 4;
  int rl = lane >> 2;            // row within 16-row chunk
  int cl = (lane & 3) * 8;       // col elems within 32
  f32x4 accP[4][2] = {};
  f32x4 accG[4][2] = {};

  const bf16_t* Xb = X + (size_t)m0 * K;
  const bf16_t* Wmb = Wtm + (size_t)n0 * K;
  const bf16_t* Wgb = Wtg + (size_t)n0 * K;
  bf16_t* LA = L;
  bf16_t* LBm = L + 8192;
  bf16_t* LBg = L + 12288;

#define STAGE3(buf, kt)                                                    \
  {                                                                        \
    _Pragma("unroll")                                                      \
    for (int c = 0; c < 2; ++c) {                                          \
      int ch = wave * 2 + c;                                               \
      gld16(Xb + (size_t)(ch * 16 + rl) * K + (kt) * 32 + cl,              \
            LA + (buf) * 4096 + ch * 512);                                 \
    }                                                                      \
    size_t gob = (size_t)(wave * 16 + rl) * K + (kt) * 32 + cl;            \
    gld16(Wmb + gob, LBm + (buf) * 2048 + wave * 512);                     \
    gld16(Wgb + gob, LBg + (buf) * 2048 + wave * 512);                     \
  }

  STAGE3(0, 0);
  __syncthreads();
  int cur = 0;
  for (int kt = 0; kt < 32; ++kt) {
    if (kt < 31) STAGE3(cur ^ 1, kt + 1);
    bf16x8 af[4], bmf[2], bgf[2];
#pragma unroll
    for (int i = 0; i < 4; ++i)
      af[i] = *reinterpret_cast<const bf16x8*>(
          &LA[cur * 4096 + (wm * 64 + i * 16 + lr) * 32 + lk * 8]);
#pragma unroll
    for (int j = 0; j < 2; ++j) {
      bmf[j] = *reinterpret_cast<const bf16x8*>(
          &LBm[cur * 2048 + (wn * 32 + j * 16 + lr) * 32 + lk * 8]);
      bgf[j] = *reinterpret_cast<const bf16x8*>(
          &LBg[cur * 2048 + (wn * 32 + j * 16 + lr) * 32 + lk * 8]);
    }
#pragma unroll
    for (int i = 0; i < 4; ++i)
#pragma unroll
      for (int j = 0; j < 2; ++j) {
        accP[i][j] = __builtin_amdgcn_mfma_f32_16x16x32_bf16(af[i], bmf[j], accP[i][j], 0, 0, 0);
        accG[i][j] = __builtin_amdgcn_mfma_f32_16x16x32_bf16(af[i], bgf[j], accG[i][j], 0, 0, 0);
      }
    __syncthreads();
    cur ^= 1;
  }
#undef STAGE3

  // epilogue: gm = sigmoid(G)*P -> LDS tile (bf16 [128][GP], reuses L)
  bf16_t* G = L;
#pragma unroll
  for (int j = 0; j < 2; ++j) {
    int col = wn * 32 + j * 16 + lr;
    float bmv = bm[n0 + col], bgv = bg[n0 + col];
#pragma unroll
    for (int i = 0; i < 4; ++i) {
      int rbase = wm * 64 + i * 16 + lk * 4;
#pragma unroll
      for (int r = 0; r < 4; ++r) {
        float p = accP[i][j][r] + bmv;
        float g = accG[i][j][r] + bgv;
        float s = 1.f / (1.f + __expf(-g));
        G[(rbase + r) * GP + col] = (bf16_t)(s * p);
      }
    }
  }
  __syncthreads();
  // in-chunk cumsum over 128 rows; 4 threads per column (two-pass prefix)
  {
    int col = tid & 63;
    int q = tid >> 6;                 // quarter: rows q*32 .. q*32+31
    float lsum = 0.f;
#pragma unroll 8
    for (int r = 0; r < 32; ++r)
      lsum += (float)G[(q * 32 + r) * GP + col];
    tot[q][col] = lsum;
    __syncthreads();
    float run = 0.f;
#pragma unroll
    for (int qq = 0; qq < 3; ++qq)
      if (qq < q) run += tot[qq][col];
    int gc = n0 + col;                // global col = h*64 + d
    size_t obase = (size_t)(m0 + q * 32) * N + gc;
#pragma unroll 8
    for (int r = 0; r < 32; ++r) {
      run += (float)G[(q * 32 + r) * GP + col];
      lcm[obase + (size_t)r * N] = (bf16_t)run;
    }
    if (q == 3) {
      int bb = m0 >> 12;              // batch
      int ci = (m0 >> 7) & 31;        // chunk index
      csum[(((size_t)bb * Hn + (gc >> 6)) * NCn + ci) * 64 + (gc & 63)] = run;
    }
  }
}

// ---------------- cards = LN(carryLN + shifted lcm), carry fused ----------------
// Block = one (bh, ci). Computes its own carry prefix from csum + LN, then the
// per-row cards LN (two-pass). Contiguous bf16 output [blk][128][64].
__global__ __launch_bounds__(256) void k_cards(
    const bf16_t* __restrict__ lcm, const float* __restrict__ csum,
    const float* __restrict__ crg, const float* __restrict__ crb,
    const float* __restrict__ cg, const float* __restrict__ cb,
    bf16_t* __restrict__ cards) {
  int blk = blockIdx.x;          // bh*32 + ci
  int ci = blk & 31, bh = blk >> 5;
  int h = bh & 15, b = bh >> 4;
  int wave = threadIdx.x >> 6, lane = threadIdx.x & 63;
  int lg = lane >> 3;   // row offset within an 8-row batch
  int le = lane & 7;    // which 8-elem slice of d
  int d0 = le * 8;
  size_t xrow0 = (size_t)(b * Tn + ci * CSn);

  // carry prefix over chunks < ci, then LN over d (shared by all rows)
  float cv[8] = {0.f, 0.f, 0.f, 0.f, 0.f, 0.f, 0.f, 0.f};
  for (int k = 0; k < ci; ++k) {
    const float* cp = csum + ((size_t)bh * NCn + k) * 64 + d0;
    float4 a = *reinterpret_cast<const float4*>(cp);
    float4 c = *reinterpret_cast<const float4*>(cp + 4);
    cv[0] += a.x; cv[1] += a.y; cv[2] += a.z; cv[3] += a.w;
    cv[4] += c.x; cv[5] += c.y; cv[6] += c.z; cv[7] += c.w;
  }
  float ncv[8], ggv[8], bbv[8];
  {
    float s = 0.f;
#pragma unroll
    for (int e = 0; e < 8; ++e) s += cv[e];
    s += __shfl_xor(s, 1, 64);
    s += __shfl_xor(s, 2, 64);
    s += __shfl_xor(s, 4, 64);
    float mean = s * (1.f / 64.f);
    float q = 0.f;
#pragma unroll
    for (int e = 0; e < 8; ++e) { float dv = cv[e] - mean; q += dv * dv; }
    q += __shfl_xor(q, 1, 64);
    q += __shfl_xor(q, 2, 64);
    q += __shfl_xor(q, 4, 64);
    float rs = rsqrtf(q * (1.f / 64.f) + 1e-5f);
#pragma unroll
    for (int e = 0; e < 8; ++e) {
      ncv[e] = (cv[e] - mean) * rs * crg[d0 + e] + crb[d0 + e];
      ggv[e] = cg[d0 + e];
      bbv[e] = cb[d0 + e];
    }
  }
#pragma unroll
  for (int it = 0; it < 4; ++it) {
    int pr = wave * 32 + it * 8 + lg;   // 0..127
    float v[8];
    if (pr > 0) {
      bf16x8 lv = *reinterpret_cast<const bf16x8*>(
          lcm + (xrow0 + pr - 1) * Cn + h * Dn + d0);
#pragma unroll
      for (int e = 0; e < 8; ++e) v[e] = (float)lv[e] + ncv[e];
    } else {
#pragma unroll
      for (int e = 0; e < 8; ++e) v[e] = ncv[e];
    }
    float s = 0.f;
#pragma unroll
    for (int e = 0; e < 8; ++e) s += v[e];
    s += __shfl_xor(s, 1, 64);
    s += __shfl_xor(s, 2, 64);
    s += __shfl_xor(s, 4, 64);
    float mean = s * (1.f / 64.f);
    float q = 0.f;
#pragma unroll
    for (int e = 0; e < 8; ++e) { float dv = v[e] - mean; q += dv * dv; }
    q += __shfl_xor(q, 1, 64);
    q += __shfl_xor(q, 2, 64);
    q += __shfl_xor(q, 4, 64);
    float rs = rsqrtf(q * (1.f / 64.f) + 1e-5f);
    bf16x8 o;
#pragma unroll
    for (int e = 0; e < 8; ++e)
      o[e] = (bf16_t)((v[e] - mean) * rs * ggv[e] + bbv[e]);
    *reinterpret_cast<bf16x8*>(cards + ((size_t)blk * CSn + pr) * 64 + d0) = o;
  }
}

// ---------------- ho1 -> gelu -> ho2 per (b,h,chunk) ---------------------------
// ALL A-fragments (x and cards) loaded directly from global into registers —
// neither has cross-wave LDS reuse. LDS used only for the h tile. One barrier.
__global__ __launch_bounds__(256, 3) void k_ho_fused(
    const bf16_t* __restrict__ X, const bf16_t* __restrict__ cards,
    const bf16_t* __restrict__ W1t, const float* __restrict__ b1,
    const bf16_t* __restrict__ W2t, const float* __restrict__ b2,
    bf16_t* __restrict__ ho) {
  __shared__ __align__(16) bf16_t S[128 * 136];  // h tile
  int tid = threadIdx.x;
  int blk = blockIdx.x;
  int ci = blk & 31, bh = blk >> 5;
  int h = bh & 15, b = bh >> 4;
  int wave = tid >> 6, lane = tid & 63;
  int wm = wave >> 1, wn = wave & 1;
  int lr = lane & 15, lk = lane >> 4;
  size_t xrow0 = (size_t)(b * Tn + ci * CSn);

  // A-fragments: ks 0,1 from x; ks 2,3 from cards (both contiguous 16B/lane)
  bf16x8 af[4][4];  // [ks][i]
#pragma unroll
  for (int i = 0; i < 4; ++i) {
    const bf16_t* xr = X + (xrow0 + wm * 64 + i * 16 + lr) * Cn + h * Dn + lk * 8;
    af[0][i] = *reinterpret_cast<const bf16x8*>(xr);
    af[1][i] = *reinterpret_cast<const bf16x8*>(xr + 32);
    const bf16_t* cr = cards + ((size_t)blk * CSn + wm * 64 + i * 16 + lr) * 64 + lk * 8;
    af[2][i] = *reinterpret_cast<const bf16x8*>(cr);
    af[3][i] = *reinterpret_cast<const bf16x8*>(cr + 32);
  }

  // ho1: wave tile 64x64
  f32x4 acc[4][4] = {};
#pragma unroll
  for (int ks = 0; ks < 4; ++ks) {
    bf16x8 bfr[4];
#pragma unroll
    for (int j = 0; j < 4; ++j)
      bfr[j] = *reinterpret_cast<const bf16x8*>(
          W1t + (size_t)(wn * 64 + j * 16 + lr) * 128 + ks * 32 + lk * 8);
#pragma unroll
    for (int i = 0; i < 4; ++i)
#pragma unroll
      for (int j = 0; j < 4; ++j)
        acc[i][j] = __builtin_amdgcn_mfma_f32_16x16x32_bf16(af[ks][i], bfr[j], acc[i][j], 0, 0, 0);
  }
  // h = gelu(acc + b1) into S as [128][136]
#pragma unroll
  for (int j = 0; j < 4; ++j) {
    int col = wn * 64 + j * 16 + lr;
    float bv = b1[col];
#pragma unroll
    for (int i = 0; i < 4; ++i) {
      int rbase = wm * 64 + i * 16 + lk * 4;
#pragma unroll
      for (int r = 0; r < 4; ++r)
        S[(rbase + r) * 136 + col] = (bf16_t)gelu_f(acc[i][j][r] + bv);
    }
  }
  __syncthreads();
  // ho2: wave tile 32x64
  f32x4 acc2[2][4] = {};
#pragma unroll
  for (int ks = 0; ks < 4; ++ks) {
    bf16x8 ha[2], bfr[4];
#pragma unroll
    for (int i = 0; i < 2; ++i)
      ha[i] = *reinterpret_cast<const bf16x8*>(
          &S[(wave * 32 + i * 16 + lr) * 136 + ks * 32 + lk * 8]);
#pragma unroll
    for (int j = 0; j < 4; ++j)
      bfr[j] = *reinterpret_cast<const bf16x8*>(
          W2t + (size_t)(j * 16 + lr) * 128 + ks * 32 + lk * 8);
#pragma unroll
    for (int i = 0; i < 2; ++i)
#pragma unroll
      for (int j = 0; j < 4; ++j)
        acc2[i][j] = __builtin_amdgcn_mfma_f32_16x16x32_bf16(ha[i], bfr[j], acc2[i][j], 0, 0, 0);
  }
#pragma unroll
  for (int j = 0; j < 4; ++j) {
    int dd = j * 16 + lr;
    float bv = b2[dd];
#pragma unroll
    for (int i = 0; i < 2; ++i) {
      int pbase = wave * 32 + i * 16 + lk * 4;
#pragma unroll
      for (int r = 0; r < 4; ++r)
        ho[(xrow0 + pbase + r) * Cn + h * Dn + dd] = (bf16_t)(acc2[i][j][r] + bv);
    }
  }
}

// ---------------- proj GEMM: out = A @ Wt^T + bias (bf16 out), 2-phase dbuf -----
__global__ __launch_bounds__(256, 3) void k_gemm_bt(
    const bf16_t* __restrict__ A, const bf16_t* __restrict__ Wt,
    const float* __restrict__ bias, bf16_t* __restrict__ out) {
  constexpr int K = Cn, N = Cn;
  __shared__ __align__(16) bf16_t L[4][128 * 32];  // A0 A1 B0 B1
  int tid = threadIdx.x;
  int Lb = blockIdx.x + 8 * blockIdx.y;
  int xcd = Lb & 7, jj = Lb >> 3;
  int nb = jj & 7, mb = xcd + 8 * (jj >> 3);
  int m0 = mb * 128, n0 = nb * 128;
  int wave = tid >> 6, lane = tid & 63;
  int wm = wave >> 1, wn = wave & 1;
  int lr = lane & 15, lk = lane >> 4;
  int rl = lane >> 2, cl = (lane & 3) * 8;
  f32x4 acc[4][4] = {};
  const bf16_t* Ab = A + (size_t)m0 * K;
  const bf16_t* Wb = Wt + (size_t)n0 * K;

#define STAGE2(buf, kt)                                                    \
  {                                                                        \
    _Pragma("unroll")                                                      \
    for (int c = 0; c < 2; ++c) {                                          \
      int ch = wave * 2 + c;                                               \
      size_t go = (size_t)(ch * 16 + rl) * K + (kt) * 32 + cl;             \
      int lo = ch * 512;                                                   \
      gld16(Ab + go, &L[0 + (buf)][lo]);                                   \
      gld16(Wb + go, &L[2 + (buf)][lo]);                                   \
    }                                                                      \
  }

  STAGE2(0, 0);
  __syncthreads();
  int cur = 0;
  for (int kt = 0; kt < 32; ++kt) {
    if (kt < 31) STAGE2(cur ^ 1, kt + 1);
    bf16x8 af[4], bfr[4];
#pragma unroll
    for (int i = 0; i < 4; ++i)
      af[i] = *reinterpret_cast<const bf16x8*>(&L[0 + cur][(wm * 64 + i * 16 + lr) * 32 + lk * 8]);
#pragma unroll
    for (int j = 0; j < 4; ++j)
      bfr[j] = *reinterpret_cast<const bf16x8*>(&L[2 + cur][(wn * 64 + j * 16 + lr) * 32 + lk * 8]);
#pragma unroll
    for (int i = 0; i < 4; ++i)
#pragma unroll
      for (int j = 0; j < 4; ++j)
        acc[i][j] = __builtin_amdgcn_mfma_f32_16x16x32_bf16(af[i], bfr[j], acc[i][j], 0, 0, 0);
    __syncthreads();
    cur ^= 1;
  }
#undef STAGE2
#pragma unroll
  for (int j = 0; j < 4; ++j) {
    int col = n0 + wn * 64 + j * 16 + lr;
    float bv = bias[col];
#pragma unroll
    for (int i = 0; i < 4; ++i) {
      int rbase = m0 + wm * 64 + i * 16 + lk * 4;
#pragma unroll
      for (int r = 0; r < 4; ++r)
        out[(size_t)(rbase + r) * N + col] = (bf16_t)(acc[i][j][r] + bv);
    }
  }
}

// ---------------- final LN over C + residual (bf16 pre + bf16 x, fp32 out) ------
__global__ __launch_bounds__(256) void k_ln_residual(
    const bf16_t* __restrict__ pre, const bf16_t* __restrict__ Xb,
    const float* __restrict__ g, const float* __restrict__ be,
    float* __restrict__ out) {
  int row = blockIdx.x, t = threadIdx.x;
  size_t base = (size_t)row * Cn + t * 4;
  bf16x4 pv4 = *reinterpret_cast<const bf16x4*>(pre + base);
  float v0 = (float)pv4[0], v1 = (float)pv4[1], v2 = (float)pv4[2], v3 = (float)pv4[3];
  float s = v0 + v1 + v2 + v3;
  float q = v0 * v0 + v1 * v1 + v2 * v2 + v3 * v3;
  s = wsum64(s);
  q = wsum64(q);
  __shared__ float red[8];
  int wv = t >> 6, ln = t & 63;
  if (ln == 0) { red[wv] = s; red[4 + wv] = q; }
  __syncthreads();
  float tot = red[0] + red[1] + red[2] + red[3];
  float totq = red[4] + red[5] + red[6] + red[7];
  float mean = tot * (1.f / 1024.f);
  float var = totq * (1.f / 1024.f) - mean * mean;
  float rs = rsqrtf(fmaxf(var, 0.f) + 1e-5f);
  bf16x4 xv4 = *reinterpret_cast<const bf16x4*>(Xb + base);
  float4 gv = *reinterpret_cast<const float4*>(g + t * 4);
  float4 bv = *reinterpret_cast<const float4*>(be + t * 4);
  float4 o;
  o.x = (v0 - mean) * rs * gv.x + bv.x + (float)xv4[0];
  o.y = (v1 - mean) * rs * gv.y + bv.y + (float)xv4[1];
  o.z = (v2 - mean) * rs * gv.z + bv.z + (float)xv4[2];
  o.w = (v3 - mean) * rs * gv.w + bv.w + (float)xv4[3];
  *reinterpret_cast<float4*>(out + base) = o;
}

extern "C" void kernel_launch(void* const* d_in, const int* in_sizes, int n_in,
                              void* d_out, int out_size, void* d_ws, size_t ws_size,
                              hipStream_t stream) {
  const float* x       = (const float*)d_in[0];
  const float* mark_W  = (const float*)d_in[1];
  const float* mark_b  = (const float*)d_in[2];
  const float* gate_W  = (const float*)d_in[3];
  const float* gate_b  = (const float*)d_in[4];
  const float* carry_g = (const float*)d_in[5];
  const float* carry_b = (const float*)d_in[6];
  const float* card_g  = (const float*)d_in[7];
  const float* card_b  = (const float*)d_in[8];
  const float* ho1_W   = (const float*)d_in[9];
  const float* ho1_b   = (const float*)d_in[10];
  const float* ho2_W   = (const float*)d_in[11];
  const float* ho2_b   = (const float*)d_in[12];
  const float* proj_W  = (const float*)d_in[13];
  const float* proj_b  = (const float*)d_in[14];
  const float* ln_g    = (const float*)d_in[15];
  const float* ln_b    = (const float*)d_in[16];
  float* out = (float*)d_out;

  char* ws = (char*)d_ws;
  bf16_t* xbf    = (bf16_t*)(ws + 0);          // live until ln_residual
  bf16_t* gm     = (bf16_t*)(ws + 33554432);   // lcm (cumsum'd gm)
  bf16_t* cards  = (bf16_t*)(ws + 67108864);   // contiguous cards; dead after ho_fused
  bf16_t* outpre = (bf16_t*)(ws + 67108864);   // gemm_bt output aliases cards
  bf16_t* hobuf  = (bf16_t*)(ws + 100663296);
  float*  csum   = (float*)(ws + 134217728);
  bf16_t* wtm    = (bf16_t*)(ws + 135266304);
  bf16_t* wtg    = (bf16_t*)(ws + 137363456);
  bf16_t* wtp    = (bf16_t*)(ws + 139460608);
  bf16_t* wt1    = (bf16_t*)(ws + 141557760);
  bf16_t* wt2    = (bf16_t*)(ws + 141590528);

  k_xbf<<<8192, 256, 0, stream>>>(x, xbf);
  k_transpose<<<dim3(16, 16), 256, 0, stream>>>(mark_W, wtm, 1024, 1024);
  k_transpose<<<dim3(16, 16), 256, 0, stream>>>(gate_W, wtg, 1024, 1024);
  k_transpose<<<dim3(16, 16), 256, 0, stream>>>(proj_W, wtp, 1024, 1024);
  k_transpose<<<dim3(2, 2),   256, 0, stream>>>(ho1_W, wt1, 128, 128);
  k_transpose<<<dim3(1, 2),   256, 0, stream>>>(ho2_W, wt2, 128, 64);

  k_dualgemm_gm<<<2048, 256, 0, stream>>>(xbf, wtm, wtg, mark_b, gate_b, gm, csum);
  k_cards<<<2048, 256, 0, stream>>>(gm, csum, carry_g, carry_b, card_g, card_b, cards);
  k_ho_fused<<<2048, 256, 0, stream>>>(xbf, cards, wt1, ho1_b, wt2, ho2_b, hobuf);
  k_gemm_bt<<<dim3(8, 128), 256, 0, stream>>>(hobuf, wtp, proj_b, outpre);
  k_ln_residual<<<16384, 256, 0, stream>>>(outpre, xbf, ln_g, ln_b, out);
}

// Round 12
// 265.789 us; speedup vs baseline: 1.0487x; 1.0487x over previous
//
#include <hip/hip_runtime.h>
#include <hip/hip_bf16.h>

typedef __bf16 bf16_t;
typedef __attribute__((ext_vector_type(8))) __bf16 bf16x8;
typedef __attribute__((ext_vector_type(4))) __bf16 bf16x4;
typedef __attribute__((ext_vector_type(4))) float f32x4;

static constexpr int Bn = 4, Tn = 4096, Cn = 1024, Hn = 16, CSn = 128, Dn = 64, NCn = 32;

#define DEVINL __device__ __forceinline__

DEVINL float wsum64(float v) {
  v += __shfl_xor(v, 32, 64);
  v += __shfl_xor(v, 16, 64);
  v += __shfl_xor(v, 8, 64);
  v += __shfl_xor(v, 4, 64);
  v += __shfl_xor(v, 2, 64);
  v += __shfl_xor(v, 1, 64);
  return v;
}

// fast erf-based GELU (A&S 7.1.26, |erf err| <= 1.5e-7, far below bf16 rounding)
DEVINL float gelu_f(float v) {
  float x = v * 0.70710678f;
  float ax = fabsf(x);
  float t = 1.f / (1.f + 0.3275911f * ax);
  float poly = t * (0.254829592f +
               t * (-0.284496736f +
               t * (1.421413741f +
               t * (-1.453152027f +
               t * 1.061405429f))));
  float e = __expf(-ax * ax);
  float erfax = 1.f - poly * e;
  float erfx = copysignf(erfax, x);
  return 0.5f * v * (1.f + erfx);
}

// direct global->LDS, 16B per lane; LDS dest is wave-uniform base + lane*16
DEVINL void gld16(const bf16_t* g, bf16_t* l) {
  __builtin_amdgcn_global_load_lds(
      (const __attribute__((address_space(1))) unsigned int*)(g),
      (__attribute__((address_space(3))) unsigned int*)(l), 16, 0, 0);
}

// ------------- x fp32 -> bf16 (contiguous) -------------------------------------
__global__ __launch_bounds__(256) void k_xbf(const float* __restrict__ in,
                                             bf16_t* __restrict__ out) {
  int i = blockIdx.x * 256 + threadIdx.x;  // one per 8 elements
  float4 a = *reinterpret_cast<const float4*>(in + (size_t)i * 8);
  float4 b = *reinterpret_cast<const float4*>(in + (size_t)i * 8 + 4);
  bf16x8 o = {(bf16_t)a.x, (bf16_t)a.y, (bf16_t)a.z, (bf16_t)a.w,
              (bf16_t)b.x, (bf16_t)b.y, (bf16_t)b.z, (bf16_t)b.w};
  *reinterpret_cast<bf16x8*>(out + (size_t)i * 8) = o;
}

// ------------- transpose fp32 (rows x cols) -> bf16 (cols x rows) --------------
__global__ void k_transpose(const float* __restrict__ in, bf16_t* __restrict__ out,
                            int rows, int cols) {
  __shared__ float tile[64][65];
  int c0 = blockIdx.x * 64, r0 = blockIdx.y * 64;
  int tx = threadIdx.x & 63, ty = threadIdx.x >> 6;
#pragma unroll
  for (int i = ty; i < 64; i += 4)
    tile[i][tx] = in[(size_t)(r0 + i) * cols + c0 + tx];
  __syncthreads();
#pragma unroll
  for (int i = ty; i < 64; i += 4)
    out[(size_t)(c0 + i) * rows + r0 + tx] = (bf16_t)tile[tx][i];
}

// ---------------- fused dual GEMM + sigmoid*mul + chunk cumsum ------------------
// Block tile 128(M) x 64(N) = one (b,chunk) x one head. BK=64, 2-phase dbuf.
// Staging uses both-sides XOR swizzle: source slot = (lane&7)^(lane>>3),
// frag read slot = (ks*4+lk)^(row&7) -> conflict-free ds_read_b128.
__global__ __launch_bounds__(256, 2) void k_dualgemm_gm(
    const bf16_t* __restrict__ X, const bf16_t* __restrict__ Wtm,
    const bf16_t* __restrict__ Wtg, const float* __restrict__ bm,
    const float* __restrict__ bg, bf16_t* __restrict__ lcm,
    float* __restrict__ csum) {
  constexpr int K = Cn, N = Cn;
  constexpr int GP = 68;  // padded G-tile stride
  __shared__ __align__(16) bf16_t L[32768];  // A[2][8192] Bm[2][4096] Bg[2][4096]
  __shared__ float tot[4][64];
  int tid = threadIdx.x;
  int Lb = blockIdx.x;            // 0..2047
  int xcd = Lb & 7, jj = Lb >> 3; // jj 0..255
  int nb = jj & 15, mb = xcd + 8 * (jj >> 4);
  int m0 = mb * 128, n0 = nb * 64;
  int wave = tid >> 6, lane = tid & 63;
  int wm = wave >> 1, wn = wave & 1;
  int lr = lane & 15, lk = lane >> 4;
  int sr = lane >> 3;             // row within 8-row chunk
  int sc = (lane & 7) ^ sr;       // pre-swizzled source 16B-slot
  f32x4 accP[4][2] = {};
  f32x4 accG[4][2] = {};

  const bf16_t* Xb = X + (size_t)m0 * K;
  const bf16_t* Wmb = Wtm + (size_t)n0 * K;
  const bf16_t* Wgb = Wtg + (size_t)n0 * K;
  bf16_t* LA = L;            // 2 x 8192
  bf16_t* LBm = L + 16384;   // 2 x 4096
  bf16_t* LBg = L + 24576;   // 2 x 4096

#define STAGE3(buf, kt)                                                    \
  {                                                                        \
    _Pragma("unroll")                                                      \
    for (int c = 0; c < 4; ++c) {                                          \
      int r8 = wave * 32 + c * 8;                                          \
      gld16(Xb + (size_t)(r8 + sr) * K + (kt) * 64 + sc * 8,               \
            LA + (buf) * 8192 + r8 * 64);                                  \
    }                                                                      \
    _Pragma("unroll")                                                      \
    for (int c = 0; c < 2; ++c) {                                          \
      int r8 = wave * 16 + c * 8;                                          \
      size_t go = (size_t)(r8 + sr) * K + (kt) * 64 + sc * 8;              \
      gld16(Wmb + go, LBm + (buf) * 4096 + r8 * 64);                       \
      gld16(Wgb + go, LBg + (buf) * 4096 + r8 * 64);                       \
    }                                                                      \
  }

  STAGE3(0, 0);
  __syncthreads();
  int cur = 0;
  for (int kt = 0; kt < 16; ++kt) {
    if (kt < 15) STAGE3(cur ^ 1, kt + 1);
#pragma unroll
    for (int ks = 0; ks < 2; ++ks) {
      int sl = ((ks * 4 + lk) ^ (lr & 7)) * 8;
      bf16x8 af[4], bmf[2], bgf[2];
#pragma unroll
      for (int i = 0; i < 4; ++i)
        af[i] = *reinterpret_cast<const bf16x8*>(
            &LA[cur * 8192 + (wm * 64 + i * 16 + lr) * 64 + sl]);
#pragma unroll
      for (int j = 0; j < 2; ++j) {
        bmf[j] = *reinterpret_cast<const bf16x8*>(
            &LBm[cur * 4096 + (wn * 32 + j * 16 + lr) * 64 + sl]);
        bgf[j] = *reinterpret_cast<const bf16x8*>(
            &LBg[cur * 4096 + (wn * 32 + j * 16 + lr) * 64 + sl]);
      }
#pragma unroll
      for (int i = 0; i < 4; ++i)
#pragma unroll
        for (int j = 0; j < 2; ++j) {
          accP[i][j] = __builtin_amdgcn_mfma_f32_16x16x32_bf16(af[i], bmf[j], accP[i][j], 0, 0, 0);
          accG[i][j] = __builtin_amdgcn_mfma_f32_16x16x32_bf16(af[i], bgf[j], accG[i][j], 0, 0, 0);
        }
    }
    __syncthreads();
    cur ^= 1;
  }
#undef STAGE3

  // epilogue: gm = sigmoid(G)*P -> LDS tile (bf16 [128][GP], reuses L)
  bf16_t* G = L;
#pragma unroll
  for (int j = 0; j < 2; ++j) {
    int col = wn * 32 + j * 16 + lr;
    float bmv = bm[n0 + col], bgv = bg[n0 + col];
#pragma unroll
    for (int i = 0; i < 4; ++i) {
      int rbase = wm * 64 + i * 16 + lk * 4;
#pragma unroll
      for (int r = 0; r < 4; ++r) {
        float p = accP[i][j][r] + bmv;
        float g = accG[i][j][r] + bgv;
        float s = 1.f / (1.f + __expf(-g));
        G[(rbase + r) * GP + col] = (bf16_t)(s * p);
      }
    }
  }
  __syncthreads();
  // in-chunk cumsum over 128 rows; 4 threads per column (two-pass prefix)
  {
    int col = tid & 63;
    int q = tid >> 6;                 // quarter: rows q*32 .. q*32+31
    float lsum = 0.f;
#pragma unroll 8
    for (int r = 0; r < 32; ++r)
      lsum += (float)G[(q * 32 + r) * GP + col];
    tot[q][col] = lsum;
    __syncthreads();
    float run = 0.f;
#pragma unroll
    for (int qq = 0; qq < 3; ++qq)
      if (qq < q) run += tot[qq][col];
    int gc = n0 + col;                // global col = h*64 + d
    size_t obase = (size_t)(m0 + q * 32) * N + gc;
#pragma unroll 8
    for (int r = 0; r < 32; ++r) {
      run += (float)G[(q * 32 + r) * GP + col];
      lcm[obase + (size_t)r * N] = (bf16_t)run;
    }
    if (q == 3) {
      int bb = m0 >> 12;              // batch
      int ci = (m0 >> 7) & 31;        // chunk index
      csum[(((size_t)bb * Hn + (gc >> 6)) * NCn + ci) * 64 + (gc & 63)] = run;
    }
  }
}

// ---------------- cards = LN(carryLN + shifted lcm), carry fused ----------------
// Block = one (bh, ci). Computes its own carry prefix from csum + LN, then the
// per-row cards LN (two-pass). Contiguous bf16 output [blk][128][64].
__global__ __launch_bounds__(256) void k_cards(
    const bf16_t* __restrict__ lcm, const float* __restrict__ csum,
    const float* __restrict__ crg, const float* __restrict__ crb,
    const float* __restrict__ cg, const float* __restrict__ cb,
    bf16_t* __restrict__ cards) {
  int blk = blockIdx.x;          // bh*32 + ci
  int ci = blk & 31, bh = blk >> 5;
  int h = bh & 15, b = bh >> 4;
  int wave = threadIdx.x >> 6, lane = threadIdx.x & 63;
  int lg = lane >> 3;   // row offset within an 8-row batch
  int le = lane & 7;    // which 8-elem slice of d
  int d0 = le * 8;
  size_t xrow0 = (size_t)(b * Tn + ci * CSn);

  // carry prefix over chunks < ci, then LN over d (shared by all rows)
  float cv[8] = {0.f, 0.f, 0.f, 0.f, 0.f, 0.f, 0.f, 0.f};
  for (int k = 0; k < ci; ++k) {
    const float* cp = csum + ((size_t)bh * NCn + k) * 64 + d0;
    float4 a = *reinterpret_cast<const float4*>(cp);
    float4 c = *reinterpret_cast<const float4*>(cp + 4);
    cv[0] += a.x; cv[1] += a.y; cv[2] += a.z; cv[3] += a.w;
    cv[4] += c.x; cv[5] += c.y; cv[6] += c.z; cv[7] += c.w;
  }
  float ncv[8], ggv[8], bbv[8];
  {
    float s = 0.f;
#pragma unroll
    for (int e = 0; e < 8; ++e) s += cv[e];
    s += __shfl_xor(s, 1, 64);
    s += __shfl_xor(s, 2, 64);
    s += __shfl_xor(s, 4, 64);
    float mean = s * (1.f / 64.f);
    float q = 0.f;
#pragma unroll
    for (int e = 0; e < 8; ++e) { float dv = cv[e] - mean; q += dv * dv; }
    q += __shfl_xor(q, 1, 64);
    q += __shfl_xor(q, 2, 64);
    q += __shfl_xor(q, 4, 64);
    float rs = rsqrtf(q * (1.f / 64.f) + 1e-5f);
#pragma unroll
    for (int e = 0; e < 8; ++e) {
      ncv[e] = (cv[e] - mean) * rs * crg[d0 + e] + crb[d0 + e];
      ggv[e] = cg[d0 + e];
      bbv[e] = cb[d0 + e];
    }
  }
#pragma unroll
  for (int it = 0; it < 4; ++it) {
    int pr = wave * 32 + it * 8 + lg;   // 0..127
    float v[8];
    if (pr > 0) {
      bf16x8 lv = *reinterpret_cast<const bf16x8*>(
          lcm + (xrow0 + pr - 1) * Cn + h * Dn + d0);
#pragma unroll
      for (int e = 0; e < 8; ++e) v[e] = (float)lv[e] + ncv[e];
    } else {
#pragma unroll
      for (int e = 0; e < 8; ++e) v[e] = ncv[e];
    }
    float s = 0.f;
#pragma unroll
    for (int e = 0; e < 8; ++e) s += v[e];
    s += __shfl_xor(s, 1, 64);
    s += __shfl_xor(s, 2, 64);
    s += __shfl_xor(s, 4, 64);
    float mean = s * (1.f / 64.f);
    float q = 0.f;
#pragma unroll
    for (int e = 0; e < 8; ++e) { float dv = v[e] - mean; q += dv * dv; }
    q += __shfl_xor(q, 1, 64);
    q += __shfl_xor(q, 2, 64);
    q += __shfl_xor(q, 4, 64);
    float rs = rsqrtf(q * (1.f / 64.f) + 1e-5f);
    bf16x8 o;
#pragma unroll
    for (int e = 0; e < 8; ++e)
      o[e] = (bf16_t)((v[e] - mean) * rs * ggv[e] + bbv[e]);
    *reinterpret_cast<bf16x8*>(cards + ((size_t)blk * CSn + pr) * 64 + d0) = o;
  }
}

// ---------------- ho1 -> gelu -> ho2 per (b,h,chunk), LN-free (R10 version) ----
// cards staged via global_load_lds into linear LDS [128][64] with pre-swizzled
// source columns; frag reads apply the same XOR -> conflict-free.
// x half loaded directly into A-fragments. W1t/W2t read from global (L2).
__global__ __launch_bounds__(256, 4) void k_ho_fused(
    const bf16_t* __restrict__ X, const bf16_t* __restrict__ cards,
    const bf16_t* __restrict__ W1t, const float* __restrict__ b1,
    const bf16_t* __restrict__ W2t, const float* __restrict__ b2,
    bf16_t* __restrict__ ho) {
  __shared__ __align__(16) bf16_t S[128 * 136];  // phase1: cards[128][64]; phase2: h[128][136]
  int tid = threadIdx.x;
  int blk = blockIdx.x;
  int ci = blk & 31, bh = blk >> 5;
  int h = bh & 15, b = bh >> 4;
  int wave = tid >> 6, lane = tid & 63;
  int wm = wave >> 1, wn = wave & 1;
  int lr = lane & 15, lk = lane >> 4;
  size_t xrow0 = (size_t)(b * Tn + ci * CSn);

  // stage cards: each wave 4 gld16 calls, 8 rows each; source col pre-swizzled
  {
    const bf16_t* cbase = cards + (size_t)blk * CSn * 64;
#pragma unroll
    for (int c = 0; c < 4; ++c) {
      int row = wave * 32 + c * 8 + (lane >> 3);
      int c16 = (lane & 7) ^ (row & 7);
      gld16(cbase + (size_t)row * 64 + c16 * 8, S + (wave * 32 + c * 8) * 64);
    }
  }
  // x A-fragments direct from global (issued alongside staging)
  bf16x8 xf0[4], xf1[4];
#pragma unroll
  for (int i = 0; i < 4; ++i) {
    const bf16_t* xr = X + (xrow0 + wm * 64 + i * 16 + lr) * Cn + h * Dn + lk * 8;
    xf0[i] = *reinterpret_cast<const bf16x8*>(xr);
    xf1[i] = *reinterpret_cast<const bf16x8*>(xr + 32);
  }
  __syncthreads();

  // ho1: wave tile 64x64; ks 0,1 = x (reg), ks 2,3 = cards (LDS, swizzled read)
  f32x4 acc[4][4] = {};
#pragma unroll
  for (int ks = 0; ks < 4; ++ks) {
    bf16x8 af[4], bfr[4];
#pragma unroll
    for (int i = 0; i < 4; ++i) {
      if (ks == 0)      af[i] = xf0[i];
      else if (ks == 1) af[i] = xf1[i];
      else {
        int row = wm * 64 + i * 16 + lr;
        int c16 = ((ks - 2) * 4 + lk) ^ (lr & 7);
        af[i] = *reinterpret_cast<const bf16x8*>(&S[row * 64 + c16 * 8]);
      }
    }
#pragma unroll
    for (int j = 0; j < 4; ++j)
      bfr[j] = *reinterpret_cast<const bf16x8*>(
          W1t + (size_t)(wn * 64 + j * 16 + lr) * 128 + ks * 32 + lk * 8);
#pragma unroll
    for (int i = 0; i < 4; ++i)
#pragma unroll
      for (int j = 0; j < 4; ++j)
        acc[i][j] = __builtin_amdgcn_mfma_f32_16x16x32_bf16(af[i], bfr[j], acc[i][j], 0, 0, 0);
  }
  __syncthreads();
  // h = gelu(acc + b1) into S as [128][136]
#pragma unroll
  for (int j = 0; j < 4; ++j) {
    int col = wn * 64 + j * 16 + lr;
    float bv = b1[col];
#pragma unroll
    for (int i = 0; i < 4; ++i) {
      int rbase = wm * 64 + i * 16 + lk * 4;
#pragma unroll
      for (int r = 0; r < 4; ++r)
        S[(rbase + r) * 136 + col] = (bf16_t)gelu_f(acc[i][j][r] + bv);
    }
  }
  __syncthreads();
  // ho2: wave tile 32x64
  f32x4 acc2[2][4] = {};
#pragma unroll
  for (int ks = 0; ks < 4; ++ks) {
    bf16x8 af[2], bfr[4];
#pragma unroll
    for (int i = 0; i < 2; ++i)
      af[i] = *reinterpret_cast<const bf16x8*>(
          &S[(wave * 32 + i * 16 + lr) * 136 + ks * 32 + lk * 8]);
#pragma unroll
    for (int j = 0; j < 4; ++j)
      bfr[j] = *reinterpret_cast<const bf16x8*>(
          W2t + (size_t)(j * 16 + lr) * 128 + ks * 32 + lk * 8);
#pragma unroll
    for (int i = 0; i < 2; ++i)
#pragma unroll
      for (int j = 0; j < 4; ++j)
        acc2[i][j] = __builtin_amdgcn_mfma_f32_16x16x32_bf16(af[i], bfr[j], acc2[i][j], 0, 0, 0);
  }
#pragma unroll
  for (int j = 0; j < 4; ++j) {
    int dd = j * 16 + lr;
    float bv = b2[dd];
#pragma unroll
    for (int i = 0; i < 2; ++i) {
      int pbase = wave * 32 + i * 16 + lk * 4;
#pragma unroll
      for (int r = 0; r < 4; ++r)
        ho[(xrow0 + pbase + r) * Cn + h * Dn + dd] = (bf16_t)(acc2[i][j][r] + bv);
    }
  }
}

// ---------------- proj GEMM: 128x128 tile, BK=64, swizzled staging --------------
__global__ __launch_bounds__(256, 2) void k_gemm_bt(
    const bf16_t* __restrict__ A, const bf16_t* __restrict__ Wt,
    const float* __restrict__ bias, bf16_t* __restrict__ out) {
  constexpr int K = Cn, N = Cn;
  __shared__ __align__(16) bf16_t L[32768];  // A[2][8192] B[2][8192]
  int tid = threadIdx.x;
  int Lb = blockIdx.x + 8 * blockIdx.y;
  int xcd = Lb & 7, jj = Lb >> 3;
  int nb = jj & 7, mb = xcd + 8 * (jj >> 3);
  int m0 = mb * 128, n0 = nb * 128;
  int wave = tid >> 6, lane = tid & 63;
  int wm = wave >> 1, wn = wave & 1;
  int lr = lane & 15, lk = lane >> 4;
  int sr = lane >> 3;
  int sc = (lane & 7) ^ sr;
  f32x4 acc[4][4] = {};
  const bf16_t* Ab = A + (size_t)m0 * K;
  const bf16_t* Wb = Wt + (size_t)n0 * K;
  bf16_t* LA = L;          // 2 x 8192
  bf16_t* LB = L + 16384;  // 2 x 8192

#define STAGE2(buf, kt)                                                    \
  {                                                                        \
    _Pragma("unroll")                                                      \
    for (int c = 0; c < 4; ++c) {                                          \
      int r8 = wave * 32 + c * 8;                                          \
      size_t go = (size_t)(r8 + sr) * K + (kt) * 64 + sc * 8;              \
      gld16(Ab + go, LA + (buf) * 8192 + r8 * 64);                         \
      gld16(Wb + go, LB + (buf) * 8192 + r8 * 64);                         \
    }                                                                      \
  }

  STAGE2(0, 0);
  __syncthreads();
  int cur = 0;
  for (int kt = 0; kt < 16; ++kt) {
    if (kt < 15) STAGE2(cur ^ 1, kt + 1);
#pragma unroll
    for (int ks = 0; ks < 2; ++ks) {
      int sl = ((ks * 4 + lk) ^ (lr & 7)) * 8;
      bf16x8 af[4], bfr[4];
#pragma unroll
      for (int i = 0; i < 4; ++i)
        af[i] = *reinterpret_cast<const bf16x8*>(
            &LA[cur * 8192 + (wm * 64 + i * 16 + lr) * 64 + sl]);
#pragma unroll
      for (int j = 0; j < 4; ++j)
        bfr[j] = *reinterpret_cast<const bf16x8*>(
            &LB[cur * 8192 + (wn * 64 + j * 16 + lr) * 64 + sl]);
#pragma unroll
      for (int i = 0; i < 4; ++i)
#pragma unroll
        for (int j = 0; j < 4; ++j)
          acc[i][j] = __builtin_amdgcn_mfma_f32_16x16x32_bf16(af[i], bfr[j], acc[i][j], 0, 0, 0);
    }
    __syncthreads();
    cur ^= 1;
  }
#undef STAGE2
#pragma unroll
  for (int j = 0; j < 4; ++j) {
    int col = n0 + wn * 64 + j * 16 + lr;
    float bv = bias[col];
#pragma unroll
    for (int i = 0; i < 4; ++i) {
      int rbase = m0 + wm * 64 + i * 16 + lk * 4;
#pragma unroll
      for (int r = 0; r < 4; ++r)
        out[(size_t)(rbase + r) * N + col] = (bf16_t)(acc[i][j][r] + bv);
    }
  }
}

// ---------------- final LN over C + residual (bf16 pre + bf16 x, fp32 out) ------
__global__ __launch_bounds__(256) void k_ln_residual(
    const bf16_t* __restrict__ pre, const bf16_t* __restrict__ Xb,
    const float* __restrict__ g, const float* __restrict__ be,
    float* __restrict__ out) {
  int row = blockIdx.x, t = threadIdx.x;
  size_t base = (size_t)row * Cn + t * 4;
  bf16x4 pv4 = *reinterpret_cast<const bf16x4*>(pre + base);
  float v0 = (float)pv4[0], v1 = (float)pv4[1], v2 = (float)pv4[2], v3 = (float)pv4[3];
  float s = v0 + v1 + v2 + v3;
  float q = v0 * v0 + v1 * v1 + v2 * v2 + v3 * v3;
  s = wsum64(s);
  q = wsum64(q);
  __shared__ float red[8];
  int wv = t >> 6, ln = t & 63;
  if (ln == 0) { red[wv] = s; red[4 + wv] = q; }
  __syncthreads();
  float tot = red[0] + red[1] + red[2] + red[3];
  float totq = red[4] + red[5] + red[6] + red[7];
  float mean = tot * (1.f / 1024.f);
  float var = totq * (1.f / 1024.f) - mean * mean;
  float rs = rsqrtf(fmaxf(var, 0.f) + 1e-5f);
  bf16x4 xv4 = *reinterpret_cast<const bf16x4*>(Xb + base);
  float4 gv = *reinterpret_cast<const float4*>(g + t * 4);
  float4 bv = *reinterpret_cast<const float4*>(be + t * 4);
  float4 o;
  o.x = (v0 - mean) * rs * gv.x + bv.x + (float)xv4[0];
  o.y = (v1 - mean) * rs * gv.y + bv.y + (float)xv4[1];
  o.z = (v2 - mean) * rs * gv.z + bv.z + (float)xv4[2];
  o.w = (v3 - mean) * rs * gv.w + bv.w + (float)xv4[3];
  *reinterpret_cast<float4*>(out + base) = o;
}

extern "C" void kernel_launch(void* const* d_in, const int* in_sizes, int n_in,
                              void* d_out, int out_size, void* d_ws, size_t ws_size,
                              hipStream_t stream) {
  const float* x       = (const float*)d_in[0];
  const float* mark_W  = (const float*)d_in[1];
  const float* mark_b  = (const float*)d_in[2];
  const float* gate_W  = (const float*)d_in[3];
  const float* gate_b  = (const float*)d_in[4];
  const float* carry_g = (const float*)d_in[5];
  const float* carry_b = (const float*)d_in[6];
  const float* card_g  = (const float*)d_in[7];
  const float* card_b  = (const float*)d_in[8];
  const float* ho1_W   = (const float*)d_in[9];
  const float* ho1_b   = (const float*)d_in[10];
  const float* ho2_W   = (const float*)d_in[11];
  const float* ho2_b   = (const float*)d_in[12];
  const float* proj_W  = (const float*)d_in[13];
  const float* proj_b  = (const float*)d_in[14];
  const float* ln_g    = (const float*)d_in[15];
  const float* ln_b    = (const float*)d_in[16];
  float* out = (float*)d_out;

  char* ws = (char*)d_ws;
  bf16_t* xbf    = (bf16_t*)(ws + 0);          // live until ln_residual
  bf16_t* gm     = (bf16_t*)(ws + 33554432);   // lcm (cumsum'd gm)
  bf16_t* cards  = (bf16_t*)(ws + 67108864);   // contiguous cards; dead after ho_fused
  bf16_t* outpre = (bf16_t*)(ws + 67108864);   // gemm_bt output aliases cards
  bf16_t* hobuf  = (bf16_t*)(ws + 100663296);
  float*  csum   = (float*)(ws + 134217728);
  bf16_t* wtm    = (bf16_t*)(ws + 135266304);
  bf16_t* wtg    = (bf16_t*)(ws + 137363456);
  bf16_t* wtp    = (bf16_t*)(ws + 139460608);
  bf16_t* wt1    = (bf16_t*)(ws + 141557760);
  bf16_t* wt2    = (bf16_t*)(ws + 141590528);

  k_xbf<<<8192, 256, 0, stream>>>(x, xbf);
  k_transpose<<<dim3(16, 16), 256, 0, stream>>>(mark_W, wtm, 1024, 1024);
  k_transpose<<<dim3(16, 16), 256, 0, stream>>>(gate_W, wtg, 1024, 1024);
  k_transpose<<<dim3(16, 16), 256, 0, stream>>>(proj_W, wtp, 1024, 1024);
  k_transpose<<<dim3(2, 2),   256, 0, stream>>>(ho1_W, wt1, 128, 128);
  k_transpose<<<dim3(1, 2),   256, 0, stream>>>(ho2_W, wt2, 128, 64);

  k_dualgemm_gm<<<2048, 256, 0, stream>>>(xbf, wtm, wtg, mark_b, gate_b, gm, csum);
  k_cards<<<2048, 256, 0, stream>>>(gm, csum, carry_g, carry_b, card_g, card_b, cards);
  k_ho_fused<<<2048, 256, 0, stream>>>(xbf, cards, wt1, ho1_b, wt2, ho2_b, hobuf);
  k_gemm_bt<<<dim3(8, 128), 256, 0, stream>>>(hobuf, wtp, proj_b, outpre);
  k_ln_residual<<<16384, 256, 0, stream>>>(outpre, xbf, ln_g, ln_b, out);
}

// Round 13
// 260.413 us; speedup vs baseline: 1.0703x; 1.0206x over previous
//
#include <hip/hip_runtime.h>
#include <hip/hip_bf16.h>

typedef __bf16 bf16_t;
typedef __attribute__((ext_vector_type(8))) __bf16 bf16x8;
typedef __attribute__((ext_vector_type(4))) __bf16 bf16x4;
typedef __attribute__((ext_vector_type(4))) float f32x4;

static constexpr int Bn = 4, Tn = 4096, Cn = 1024, Hn = 16, CSn = 128, Dn = 64, NCn = 32;

#define DEVINL __device__ __forceinline__

DEVINL float wsum64(float v) {
  v += __shfl_xor(v, 32, 64);
  v += __shfl_xor(v, 16, 64);
  v += __shfl_xor(v, 8, 64);
  v += __shfl_xor(v, 4, 64);
  v += __shfl_xor(v, 2, 64);
  v += __shfl_xor(v, 1, 64);
  return v;
}

// fast erf-based GELU (A&S 7.1.26, |erf err| <= 1.5e-7, far below bf16 rounding)
DEVINL float gelu_f(float v) {
  float x = v * 0.70710678f;
  float ax = fabsf(x);
  float t = 1.f / (1.f + 0.3275911f * ax);
  float poly = t * (0.254829592f +
               t * (-0.284496736f +
               t * (1.421413741f +
               t * (-1.453152027f +
               t * 1.061405429f))));
  float e = __expf(-ax * ax);
  float erfax = 1.f - poly * e;
  float erfx = copysignf(erfax, x);
  return 0.5f * v * (1.f + erfx);
}

// direct global->LDS, 16B per lane; LDS dest is wave-uniform base + lane*16
DEVINL void gld16(const bf16_t* g, bf16_t* l) {
  __builtin_amdgcn_global_load_lds(
      (const __attribute__((address_space(1))) unsigned int*)(g),
      (__attribute__((address_space(3))) unsigned int*)(l), 16, 0, 0);
}

// ------------- x fp32 -> bf16 (contiguous) -------------------------------------
__global__ __launch_bounds__(256) void k_xbf(const float* __restrict__ in,
                                             bf16_t* __restrict__ out) {
  int i = blockIdx.x * 256 + threadIdx.x;  // one per 8 elements
  float4 a = *reinterpret_cast<const float4*>(in + (size_t)i * 8);
  float4 b = *reinterpret_cast<const float4*>(in + (size_t)i * 8 + 4);
  bf16x8 o = {(bf16_t)a.x, (bf16_t)a.y, (bf16_t)a.z, (bf16_t)a.w,
              (bf16_t)b.x, (bf16_t)b.y, (bf16_t)b.z, (bf16_t)b.w};
  *reinterpret_cast<bf16x8*>(out + (size_t)i * 8) = o;
}

// ------------- transpose fp32 (rows x cols) -> bf16 (cols x rows) --------------
__global__ void k_transpose(const float* __restrict__ in, bf16_t* __restrict__ out,
                            int rows, int cols) {
  __shared__ float tile[64][65];
  int c0 = blockIdx.x * 64, r0 = blockIdx.y * 64;
  int tx = threadIdx.x & 63, ty = threadIdx.x >> 6;
#pragma unroll
  for (int i = ty; i < 64; i += 4)
    tile[i][tx] = in[(size_t)(r0 + i) * cols + c0 + tx];
  __syncthreads();
#pragma unroll
  for (int i = ty; i < 64; i += 4)
    out[(size_t)(c0 + i) * rows + r0 + tx] = (bf16_t)tile[tx][i];
}

// ---------------- fused dual GEMM + sigmoid*mul + chunk cumsum ------------------
// Block tile 128(M) x 64(N) = one (b,chunk) x one head. BK=32, 2-phase dbuf.
// (R10 config: proven fastest variant — conflicts present but non-binding.)
__global__ __launch_bounds__(256, 3) void k_dualgemm_gm(
    const bf16_t* __restrict__ X, const bf16_t* __restrict__ Wtm,
    const bf16_t* __restrict__ Wtg, const float* __restrict__ bm,
    const float* __restrict__ bg, bf16_t* __restrict__ lcm,
    float* __restrict__ csum) {
  constexpr int K = Cn, N = Cn;
  constexpr int GP = 68;  // padded G-tile stride
  __shared__ __align__(16) bf16_t L[16384];
  __shared__ float tot[4][64];
  int tid = threadIdx.x;
  int Lb = blockIdx.x;            // 0..2047
  int xcd = Lb & 7, jj = Lb >> 3; // jj 0..255
  int nb = jj & 15, mb = xcd + 8 * (jj >> 4);
  int m0 = mb * 128, n0 = nb * 64;
  int wave = tid >> 6, lane = tid & 63;
  int wm = wave >> 1, wn = wave & 1;
  int lr = lane & 15, lk = lane >> 4;
  int rl = lane >> 2;            // row within 16-row chunk
  int cl = (lane & 3) * 8;       // col elems within 32
  f32x4 accP[4][2] = {};
  f32x4 accG[4][2] = {};

  const bf16_t* Xb = X + (size_t)m0 * K;
  const bf16_t* Wmb = Wtm + (size_t)n0 * K;
  const bf16_t* Wgb = Wtg + (size_t)n0 * K;
  bf16_t* LA = L;
  bf16_t* LBm = L + 8192;
  bf16_t* LBg = L + 12288;

#define STAGE3(buf, kt)                                                    \
  {                                                                        \
    _Pragma("unroll")                                                      \
    for (int c = 0; c < 2; ++c) {                                          \
      int ch = wave * 2 + c;                                               \
      gld16(Xb + (size_t)(ch * 16 + rl) * K + (kt) * 32 + cl,              \
            LA + (buf) * 4096 + ch * 512);                                 \
    }                                                                      \
    size_t gob = (size_t)(wave * 16 + rl) * K + (kt) * 32 + cl;            \
    gld16(Wmb + gob, LBm + (buf) * 2048 + wave * 512);                     \
    gld16(Wgb + gob, LBg + (buf) * 2048 + wave * 512);                     \
  }

  STAGE3(0, 0);
  __syncthreads();
  int cur = 0;
  for (int kt = 0; kt < 32; ++kt) {
    if (kt < 31) STAGE3(cur ^ 1, kt + 1);
    bf16x8 af[4], bmf[2], bgf[2];
#pragma unroll
    for (int i = 0; i < 4; ++i)
      af[i] = *reinterpret_cast<const bf16x8*>(
          &LA[cur * 4096 + (wm * 64 + i * 16 + lr) * 32 + lk * 8]);
#pragma unroll
    for (int j = 0; j < 2; ++j) {
      bmf[j] = *reinterpret_cast<const bf16x8*>(
          &LBm[cur * 2048 + (wn * 32 + j * 16 + lr) * 32 + lk * 8]);
      bgf[j] = *reinterpret_cast<const bf16x8*>(
          &LBg[cur * 2048 + (wn * 32 + j * 16 + lr) * 32 + lk * 8]);
    }
#pragma unroll
    for (int i = 0; i < 4; ++i)
#pragma unroll
      for (int j = 0; j < 2; ++j) {
        accP[i][j] = __builtin_amdgcn_mfma_f32_16x16x32_bf16(af[i], bmf[j], accP[i][j], 0, 0, 0);
        accG[i][j] = __builtin_amdgcn_mfma_f32_16x16x32_bf16(af[i], bgf[j], accG[i][j], 0, 0, 0);
      }
    __syncthreads();
    cur ^= 1;
  }
#undef STAGE3

  // epilogue: gm = sigmoid(G)*P -> LDS tile (bf16 [128][GP], reuses L)
  bf16_t* G = L;
#pragma unroll
  for (int j = 0; j < 2; ++j) {
    int col = wn * 32 + j * 16 + lr;
    float bmv = bm[n0 + col], bgv = bg[n0 + col];
#pragma unroll
    for (int i = 0; i < 4; ++i) {
      int rbase = wm * 64 + i * 16 + lk * 4;
#pragma unroll
      for (int r = 0; r < 4; ++r) {
        float p = accP[i][j][r] + bmv;
        float g = accG[i][j][r] + bgv;
        float s = 1.f / (1.f + __expf(-g));
        G[(rbase + r) * GP + col] = (bf16_t)(s * p);
      }
    }
  }
  __syncthreads();
  // in-chunk cumsum over 128 rows; 4 threads per column (two-pass prefix)
  {
    int col = tid & 63;
    int q = tid >> 6;                 // quarter: rows q*32 .. q*32+31
    float lsum = 0.f;
#pragma unroll 8
    for (int r = 0; r < 32; ++r)
      lsum += (float)G[(q * 32 + r) * GP + col];
    tot[q][col] = lsum;
    __syncthreads();
    float run = 0.f;
#pragma unroll
    for (int qq = 0; qq < 3; ++qq)
      if (qq < q) run += tot[qq][col];
    int gc = n0 + col;                // global col = h*64 + d
    size_t obase = (size_t)(m0 + q * 32) * N + gc;
#pragma unroll 8
    for (int r = 0; r < 32; ++r) {
      run += (float)G[(q * 32 + r) * GP + col];
      lcm[obase + (size_t)r * N] = (bf16_t)run;
    }
    if (q == 3) {
      int bb = m0 >> 12;              // batch
      int ci = (m0 >> 7) & 31;        // chunk index
      csum[(((size_t)bb * Hn + (gc >> 6)) * NCn + ci) * 64 + (gc & 63)] = run;
    }
  }
}

// ---------------- exclusive carry cumsum over chunks + LN(D) --------------------
__global__ __launch_bounds__(64) void k_carry_ln(const float* __restrict__ csum,
                                                 float* __restrict__ ncar,
                                                 const float* __restrict__ g,
                                                 const float* __restrict__ be) {
  int bh = blockIdx.x;
  int d = threadIdx.x;
  float gd = g[d], bd = be[d];
  float run = 0.f;
  for (int ci = 0; ci < NCn; ++ci) {
    float v = run;  // exclusive prefix
    run += csum[((size_t)bh * NCn + ci) * 64 + d];
    float m = wsum64(v) * (1.f / 64.f);
    float dv = v - m;
    float var = wsum64(dv * dv) * (1.f / 64.f);
    ncar[((size_t)bh * NCn + ci) * 64 + d] = dv * rsqrtf(var + 1e-5f) * gd + bd;
  }
}

// ---------------- fused cards-LN + ho1 -> gelu -> ho2 per (b,h,chunk) -----------
// (R7 config: in-kernel two-pass LN into LDS right-half; x direct to A-frags.)
__global__ __launch_bounds__(256, 4) void k_ho_fused(
    const bf16_t* __restrict__ X, const bf16_t* __restrict__ lcm,
    const float* __restrict__ ncar, const float* __restrict__ cg,
    const float* __restrict__ cb, const bf16_t* __restrict__ W1t,
    const float* __restrict__ b1, const bf16_t* __restrict__ W2t,
    const float* __restrict__ b2, bf16_t* __restrict__ ho) {
  __shared__ __align__(16) bf16_t Cs[128][136];  // phase1: cards in cols 64..127; phase2: h tile
  int tid = threadIdx.x;
  int ci = blockIdx.x & 31, bh = blockIdx.x >> 5;
  int h = bh & 15, b = bh >> 4;
  int wave = tid >> 6, lane = tid & 63;
  int wm = wave >> 1, wn = wave & 1;
  int lr = lane & 15, lk = lane >> 4;
  size_t xrow0 = (size_t)(b * Tn + ci * CSn);

  // issue x A-fragments early (HBM latency hides under the cards LN below)
  bf16x8 xf0[4], xf1[4];
#pragma unroll
  for (int i = 0; i < 4; ++i) {
    const bf16_t* xr = X + (xrow0 + wm * 64 + i * 16 + lr) * Cn + h * Dn + lk * 8;
    xf0[i] = *reinterpret_cast<const bf16x8*>(xr);
    xf1[i] = *reinterpret_cast<const bf16x8*>(xr + 32);
  }

  // cards half: in-register LN (two-pass variance), 8 lanes per row x 8 elems
  {
    int lg = lane >> 3;   // row offset within an 8-row batch
    int le = lane & 7;    // which 8-elem slice of d
    int d0 = le * 8;
    const float* np = ncar + ((size_t)bh * NCn + ci) * 64 + d0;
    float ncv[8], ggv[8], bbv[8];
#pragma unroll
    for (int e = 0; e < 8; ++e) {
      ncv[e] = np[e];
      ggv[e] = cg[d0 + e];
      bbv[e] = cb[d0 + e];
    }
#pragma unroll
    for (int it = 0; it < 4; ++it) {
      int pr = wave * 32 + it * 8 + lg;   // 0..127
      float v[8];
      if (pr > 0) {
        bf16x8 lv = *reinterpret_cast<const bf16x8*>(
            lcm + (xrow0 + pr - 1) * Cn + h * Dn + d0);
#pragma unroll
        for (int e = 0; e < 8; ++e) v[e] = (float)lv[e] + ncv[e];
      } else {
#pragma unroll
        for (int e = 0; e < 8; ++e) v[e] = ncv[e];
      }
      float s = 0.f;
#pragma unroll
      for (int e = 0; e < 8; ++e) s += v[e];
      s += __shfl_xor(s, 1, 64);
      s += __shfl_xor(s, 2, 64);
      s += __shfl_xor(s, 4, 64);
      float mean = s * (1.f / 64.f);
      float q = 0.f;
#pragma unroll
      for (int e = 0; e < 8; ++e) { float dv = v[e] - mean; q += dv * dv; }
      q += __shfl_xor(q, 1, 64);
      q += __shfl_xor(q, 2, 64);
      q += __shfl_xor(q, 4, 64);
      float rs = rsqrtf(q * (1.f / 64.f) + 1e-5f);
      bf16x8 o;
#pragma unroll
      for (int e = 0; e < 8; ++e)
        o[e] = (bf16_t)((v[e] - mean) * rs * ggv[e] + bbv[e]);
      *reinterpret_cast<bf16x8*>(&Cs[pr][64 + d0]) = o;
    }
  }
  __syncthreads();
  f32x4 acc[4][4] = {};
#pragma unroll
  for (int ks = 0; ks < 4; ++ks) {
    bf16x8 af[4], bfr[4];
#pragma unroll
    for (int i = 0; i < 4; ++i) {
      if (ks == 0)      af[i] = xf0[i];
      else if (ks == 1) af[i] = xf1[i];
      else
        af[i] = *reinterpret_cast<const bf16x8*>(
            &Cs[wm * 64 + i * 16 + lr][64 + (ks - 2) * 32 + lk * 8]);
    }
#pragma unroll
    for (int j = 0; j < 4; ++j)
      bfr[j] = *reinterpret_cast<const bf16x8*>(
          W1t + (size_t)(wn * 64 + j * 16 + lr) * 128 + ks * 32 + lk * 8);
#pragma unroll
    for (int i = 0; i < 4; ++i)
#pragma unroll
      for (int j = 0; j < 4; ++j)
        acc[i][j] = __builtin_amdgcn_mfma_f32_16x16x32_bf16(af[i], bfr[j], acc[i][j], 0, 0, 0);
  }
  __syncthreads();
  // h = gelu(acc + b1) into Cs (full 128 cols)
#pragma unroll
  for (int j = 0; j < 4; ++j) {
    int col = wn * 64 + j * 16 + lr;
    float bv = b1[col];
#pragma unroll
    for (int i = 0; i < 4; ++i) {
      int rbase = wm * 64 + i * 16 + lk * 4;
#pragma unroll
      for (int r = 0; r < 4; ++r)
        Cs[rbase + r][col] = (bf16_t)gelu_f(acc[i][j][r] + bv);
    }
  }
  __syncthreads();
  f32x4 acc2[2][4] = {};
#pragma unroll
  for (int ks = 0; ks < 4; ++ks) {
    bf16x8 af[2], bfr[4];
#pragma unroll
    for (int i = 0; i < 2; ++i)
      af[i] = *reinterpret_cast<const bf16x8*>(&Cs[wave * 32 + i * 16 + lr][ks * 32 + lk * 8]);
#pragma unroll
    for (int j = 0; j < 4; ++j)
      bfr[j] = *reinterpret_cast<const bf16x8*>(
          W2t + (size_t)(j * 16 + lr) * 128 + ks * 32 + lk * 8);
#pragma unroll
    for (int i = 0; i < 2; ++i)
#pragma unroll
      for (int j = 0; j < 4; ++j)
        acc2[i][j] = __builtin_amdgcn_mfma_f32_16x16x32_bf16(af[i], bfr[j], acc2[i][j], 0, 0, 0);
  }
#pragma unroll
  for (int j = 0; j < 4; ++j) {
    int dd = j * 16 + lr;
    float bv = b2[dd];
#pragma unroll
    for (int i = 0; i < 2; ++i) {
      int pbase = wave * 32 + i * 16 + lk * 4;
#pragma unroll
      for (int r = 0; r < 4; ++r)
        ho[(xrow0 + pbase + r) * Cn + h * Dn + dd] = (bf16_t)(acc2[i][j][r] + bv);
    }
  }
}

// ---------------- proj GEMM: 128x128 tile, BK=64, swizzled staging --------------
__global__ __launch_bounds__(256, 2) void k_gemm_bt(
    const bf16_t* __restrict__ A, const bf16_t* __restrict__ Wt,
    const float* __restrict__ bias, bf16_t* __restrict__ out) {
  constexpr int K = Cn, N = Cn;
  __shared__ __align__(16) bf16_t L[32768];  // A[2][8192] B[2][8192]
  int tid = threadIdx.x;
  int Lb = blockIdx.x + 8 * blockIdx.y;
  int xcd = Lb & 7, jj = Lb >> 3;
  int nb = jj & 7, mb = xcd + 8 * (jj >> 3);
  int m0 = mb * 128, n0 = nb * 128;
  int wave = tid >> 6, lane = tid & 63;
  int wm = wave >> 1, wn = wave & 1;
  int lr = lane & 15, lk = lane >> 4;
  int sr = lane >> 3;
  int sc = (lane & 7) ^ sr;
  f32x4 acc[4][4] = {};
  const bf16_t* Ab = A + (size_t)m0 * K;
  const bf16_t* Wb = Wt + (size_t)n0 * K;
  bf16_t* LA = L;          // 2 x 8192
  bf16_t* LB = L + 16384;  // 2 x 8192

#define STAGE2(buf, kt)                                                    \
  {                                                                        \
    _Pragma("unroll")                                                      \
    for (int c = 0; c < 4; ++c) {                                          \
      int r8 = wave * 32 + c * 8;                                          \
      size_t go = (size_t)(r8 + sr) * K + (kt) * 64 + sc * 8;              \
      gld16(Ab + go, LA + (buf) * 8192 + r8 * 64);                         \
      gld16(Wb + go, LB + (buf) * 8192 + r8 * 64);                         \
    }                                                                      \
  }

  STAGE2(0, 0);
  __syncthreads();
  int cur = 0;
  for (int kt = 0; kt < 16; ++kt) {
    if (kt < 15) STAGE2(cur ^ 1, kt + 1);
#pragma unroll
    for (int ks = 0; ks < 2; ++ks) {
      int sl = ((ks * 4 + lk) ^ (lr & 7)) * 8;
      bf16x8 af[4], bfr[4];
#pragma unroll
      for (int i = 0; i < 4; ++i)
        af[i] = *reinterpret_cast<const bf16x8*>(
            &LA[cur * 8192 + (wm * 64 + i * 16 + lr) * 64 + sl]);
#pragma unroll
      for (int j = 0; j < 4; ++j)
        bfr[j] = *reinterpret_cast<const bf16x8*>(
            &LB[cur * 8192 + (wn * 64 + j * 16 + lr) * 64 + sl]);
#pragma unroll
      for (int i = 0; i < 4; ++i)
#pragma unroll
        for (int j = 0; j < 4; ++j)
          acc[i][j] = __builtin_amdgcn_mfma_f32_16x16x32_bf16(af[i], bfr[j], acc[i][j], 0, 0, 0);
    }
    __syncthreads();
    cur ^= 1;
  }
#undef STAGE2
#pragma unroll
  for (int j = 0; j < 4; ++j) {
    int col = n0 + wn * 64 + j * 16 + lr;
    float bv = bias[col];
#pragma unroll
    for (int i = 0; i < 4; ++i) {
      int rbase = m0 + wm * 64 + i * 16 + lk * 4;
#pragma unroll
      for (int r = 0; r < 4; ++r)
        out[(size_t)(rbase + r) * N + col] = (bf16_t)(acc[i][j][r] + bv);
    }
  }
}

// ---------------- final LN over C + residual (bf16 pre + bf16 x, fp32 out) ------
__global__ __launch_bounds__(256) void k_ln_residual(
    const bf16_t* __restrict__ pre, const bf16_t* __restrict__ Xb,
    const float* __restrict__ g, const float* __restrict__ be,
    float* __restrict__ out) {
  int row = blockIdx.x, t = threadIdx.x;
  size_t base = (size_t)row * Cn + t * 4;
  bf16x4 pv4 = *reinterpret_cast<const bf16x4*>(pre + base);
  float v0 = (float)pv4[0], v1 = (float)pv4[1], v2 = (float)pv4[2], v3 = (float)pv4[3];
  float s = v0 + v1 + v2 + v3;
  float q = v0 * v0 + v1 * v1 + v2 * v2 + v3 * v3;
  s = wsum64(s);
  q = wsum64(q);
  __shared__ float red[8];
  int wv = t >> 6, ln = t & 63;
  if (ln == 0) { red[wv] = s; red[4 + wv] = q; }
  __syncthreads();
  float tot = red[0] + red[1] + red[2] + red[3];
  float totq = red[4] + red[5] + red[6] + red[7];
  float mean = tot * (1.f / 1024.f);
  float var = totq * (1.f / 1024.f) - mean * mean;
  float rs = rsqrtf(fmaxf(var, 0.f) + 1e-5f);
  bf16x4 xv4 = *reinterpret_cast<const bf16x4*>(Xb + base);
  float4 gv = *reinterpret_cast<const float4*>(g + t * 4);
  float4 bv = *reinterpret_cast<const float4*>(be + t * 4);
  float4 o;
  o.x = (v0 - mean) * rs * gv.x + bv.x + (float)xv4[0];
  o.y = (v1 - mean) * rs * gv.y + bv.y + (float)xv4[1];
  o.z = (v2 - mean) * rs * gv.z + bv.z + (float)xv4[2];
  o.w = (v3 - mean) * rs * gv.w + bv.w + (float)xv4[3];
  *reinterpret_cast<float4*>(out + base) = o;
}

extern "C" void kernel_launch(void* const* d_in, const int* in_sizes, int n_in,
                              void* d_out, int out_size, void* d_ws, size_t ws_size,
                              hipStream_t stream) {
  const float* x       = (const float*)d_in[0];
  const float* mark_W  = (const float*)d_in[1];
  const float* mark_b  = (const float*)d_in[2];
  const float* gate_W  = (const float*)d_in[3];
  const float* gate_b  = (const float*)d_in[4];
  const float* carry_g = (const float*)d_in[5];
  const float* carry_b = (const float*)d_in[6];
  const float* card_g  = (const float*)d_in[7];
  const float* card_b  = (const float*)d_in[8];
  const float* ho1_W   = (const float*)d_in[9];
  const float* ho1_b   = (const float*)d_in[10];
  const float* ho2_W   = (const float*)d_in[11];
  const float* ho2_b   = (const float*)d_in[12];
  const float* proj_W  = (const float*)d_in[13];
  const float* proj_b  = (const float*)d_in[14];
  const float* ln_g    = (const float*)d_in[15];
  const float* ln_b    = (const float*)d_in[16];
  float* out = (float*)d_out;

  char* ws = (char*)d_ws;
  bf16_t* xbf    = (bf16_t*)(ws + 0);          // live until ln_residual
  bf16_t* gm     = (bf16_t*)(ws + 33554432);   // lcm (cumsum'd gm)
  bf16_t* outpre = (bf16_t*)(ws + 67108864);   // proj output (bf16)
  bf16_t* hobuf  = (bf16_t*)(ws + 100663296);
  float*  csum   = (float*)(ws + 134217728);
  float*  ncar   = (float*)(ws + 134742016);
  bf16_t* wtm    = (bf16_t*)(ws + 135266304);
  bf16_t* wtg    = (bf16_t*)(ws + 137363456);
  bf16_t* wtp    = (bf16_t*)(ws + 139460608);
  bf16_t* wt1    = (bf16_t*)(ws + 141557760);
  bf16_t* wt2    = (bf16_t*)(ws + 141590528);

  k_xbf<<<8192, 256, 0, stream>>>(x, xbf);
  k_transpose<<<dim3(16, 16), 256, 0, stream>>>(mark_W, wtm, 1024, 1024);
  k_transpose<<<dim3(16, 16), 256, 0, stream>>>(gate_W, wtg, 1024, 1024);
  k_transpose<<<dim3(16, 16), 256, 0, stream>>>(proj_W, wtp, 1024, 1024);
  k_transpose<<<dim3(2, 2),   256, 0, stream>>>(ho1_W, wt1, 128, 128);
  k_transpose<<<dim3(1, 2),   256, 0, stream>>>(ho2_W, wt2, 128, 64);

  k_dualgemm_gm<<<2048, 256, 0, stream>>>(xbf, wtm, wtg, mark_b, gate_b, gm, csum);
  k_carry_ln<<<64, 64, 0, stream>>>(csum, ncar, carry_g, carry_b);
  k_ho_fused<<<2048, 256, 0, stream>>>(xbf, gm, ncar, card_g, card_b,
                                       wt1, ho1_b, wt2, ho2_b, hobuf);
  k_gemm_bt<<<dim3(8, 128), 256, 0, stream>>>(hobuf, wtp, proj_b, outpre);
  k_ln_residual<<<16384, 256, 0, stream>>>(outpre, xbf, ln_g, ln_b, out);
}

// Round 14
// 255.085 us; speedup vs baseline: 1.0927x; 1.0209x over previous
//
#include <hip/hip_runtime.h>
#include <hip/hip_bf16.h>

typedef __bf16 bf16_t;
typedef __attribute__((ext_vector_type(8))) __bf16 bf16x8;
typedef __attribute__((ext_vector_type(4))) __bf16 bf16x4;
typedef __attribute__((ext_vector_type(4))) float f32x4;

static constexpr int Bn = 4, Tn = 4096, Cn = 1024, Hn = 16, CSn = 128, Dn = 64, NCn = 32;

#define DEVINL __device__ __forceinline__

DEVINL float wsum64(float v) {
  v += __shfl_xor(v, 32, 64);
  v += __shfl_xor(v, 16, 64);
  v += __shfl_xor(v, 8, 64);
  v += __shfl_xor(v, 4, 64);
  v += __shfl_xor(v, 2, 64);
  v += __shfl_xor(v, 1, 64);
  return v;
}

// fast erf-based GELU (A&S 7.1.26, |erf err| <= 1.5e-7, far below bf16 rounding)
DEVINL float gelu_f(float v) {
  float x = v * 0.70710678f;
  float ax = fabsf(x);
  float t = 1.f / (1.f + 0.3275911f * ax);
  float poly = t * (0.254829592f +
               t * (-0.284496736f +
               t * (1.421413741f +
               t * (-1.453152027f +
               t * 1.061405429f))));
  float e = __expf(-ax * ax);
  float erfax = 1.f - poly * e;
  float erfx = copysignf(erfax, x);
  return 0.5f * v * (1.f + erfx);
}

// direct global->LDS, 16B per lane; LDS dest is wave-uniform base + lane*16
DEVINL void gld16(const bf16_t* g, bf16_t* l) {
  __builtin_amdgcn_global_load_lds(
      (const __attribute__((address_space(1))) unsigned int*)(g),
      (__attribute__((address_space(3))) unsigned int*)(l), 16, 0, 0);
}

// ------------- x fp32 -> bf16 (contiguous) -------------------------------------
__global__ __launch_bounds__(256) void k_xbf(const float* __restrict__ in,
                                             bf16_t* __restrict__ out) {
  int i = blockIdx.x * 256 + threadIdx.x;  // one per 8 elements
  float4 a = *reinterpret_cast<const float4*>(in + (size_t)i * 8);
  float4 b = *reinterpret_cast<const float4*>(in + (size_t)i * 8 + 4);
  bf16x8 o = {(bf16_t)a.x, (bf16_t)a.y, (bf16_t)a.z, (bf16_t)a.w,
              (bf16_t)b.x, (bf16_t)b.y, (bf16_t)b.z, (bf16_t)b.w};
  *reinterpret_cast<bf16x8*>(out + (size_t)i * 8) = o;
}

// ------------- transpose fp32 (rows x cols) -> bf16 (cols x rows) --------------
__global__ void k_transpose(const float* __restrict__ in, bf16_t* __restrict__ out,
                            int rows, int cols) {
  __shared__ float tile[64][65];
  int c0 = blockIdx.x * 64, r0 = blockIdx.y * 64;
  int tx = threadIdx.x & 63, ty = threadIdx.x >> 6;
#pragma unroll
  for (int i = ty; i < 64; i += 4)
    tile[i][tx] = in[(size_t)(r0 + i) * cols + c0 + tx];
  __syncthreads();
#pragma unroll
  for (int i = ty; i < 64; i += 4)
    out[(size_t)(c0 + i) * rows + r0 + tx] = (bf16_t)tile[tx][i];
}

// ---------------- fused dual GEMM + sigmoid*mul + chunk cumsum ------------------
// Block tile 128(M) x 64(N) = one (b,chunk) x one head. BK=32, 2-phase dbuf.
__global__ __launch_bounds__(256, 3) void k_dualgemm_gm(
    const bf16_t* __restrict__ X, const bf16_t* __restrict__ Wtm,
    const bf16_t* __restrict__ Wtg, const float* __restrict__ bm,
    const float* __restrict__ bg, bf16_t* __restrict__ lcm,
    float* __restrict__ csum) {
  constexpr int K = Cn, N = Cn;
  constexpr int GP = 68;  // padded G-tile stride
  __shared__ __align__(16) bf16_t L[16384];
  __shared__ float tot[4][64];
  int tid = threadIdx.x;
  int Lb = blockIdx.x;            // 0..2047
  int xcd = Lb & 7, jj = Lb >> 3; // jj 0..255
  int nb = jj & 15, mb = xcd + 8 * (jj >> 4);
  int m0 = mb * 128, n0 = nb * 64;
  int wave = tid >> 6, lane = tid & 63;
  int wm = wave >> 1, wn = wave & 1;
  int lr = lane & 15, lk = lane >> 4;
  int rl = lane >> 2;            // row within 16-row chunk
  int cl = (lane & 3) * 8;       // col elems within 32
  f32x4 accP[4][2] = {};
  f32x4 accG[4][2] = {};

  const bf16_t* Xb = X + (size_t)m0 * K;
  const bf16_t* Wmb = Wtm + (size_t)n0 * K;
  const bf16_t* Wgb = Wtg + (size_t)n0 * K;
  bf16_t* LA = L;
  bf16_t* LBm = L + 8192;
  bf16_t* LBg = L + 12288;

#define STAGE3(buf, kt)                                                    \
  {                                                                        \
    _Pragma("unroll")                                                      \
    for (int c = 0; c < 2; ++c) {                                          \
      int ch = wave * 2 + c;                                               \
      gld16(Xb + (size_t)(ch * 16 + rl) * K + (kt) * 32 + cl,              \
            LA + (buf) * 4096 + ch * 512);                                 \
    }                                                                      \
    size_t gob = (size_t)(wave * 16 + rl) * K + (kt) * 32 + cl;            \
    gld16(Wmb + gob, LBm + (buf) * 2048 + wave * 512);                     \
    gld16(Wgb + gob, LBg + (buf) * 2048 + wave * 512);                     \
  }

  STAGE3(0, 0);
  __syncthreads();
  int cur = 0;
  for (int kt = 0; kt < 32; ++kt) {
    if (kt < 31) STAGE3(cur ^ 1, kt + 1);
    bf16x8 af[4], bmf[2], bgf[2];
#pragma unroll
    for (int i = 0; i < 4; ++i)
      af[i] = *reinterpret_cast<const bf16x8*>(
          &LA[cur * 4096 + (wm * 64 + i * 16 + lr) * 32 + lk * 8]);
#pragma unroll
    for (int j = 0; j < 2; ++j) {
      bmf[j] = *reinterpret_cast<const bf16x8*>(
          &LBm[cur * 2048 + (wn * 32 + j * 16 + lr) * 32 + lk * 8]);
      bgf[j] = *reinterpret_cast<const bf16x8*>(
          &LBg[cur * 2048 + (wn * 32 + j * 16 + lr) * 32 + lk * 8]);
    }
#pragma unroll
    for (int i = 0; i < 4; ++i)
#pragma unroll
      for (int j = 0; j < 2; ++j) {
        accP[i][j] = __builtin_amdgcn_mfma_f32_16x16x32_bf16(af[i], bmf[j], accP[i][j], 0, 0, 0);
        accG[i][j] = __builtin_amdgcn_mfma_f32_16x16x32_bf16(af[i], bgf[j], accG[i][j], 0, 0, 0);
      }
    __syncthreads();
    cur ^= 1;
  }
#undef STAGE3

  // epilogue: gm = sigmoid(G)*P -> LDS tile (bf16 [128][GP], reuses L)
  bf16_t* G = L;
#pragma unroll
  for (int j = 0; j < 2; ++j) {
    int col = wn * 32 + j * 16 + lr;
    float bmv = bm[n0 + col], bgv = bg[n0 + col];
#pragma unroll
    for (int i = 0; i < 4; ++i) {
      int rbase = wm * 64 + i * 16 + lk * 4;
#pragma unroll
      for (int r = 0; r < 4; ++r) {
        float p = accP[i][j][r] + bmv;
        float g = accG[i][j][r] + bgv;
        float s = 1.f / (1.f + __expf(-g));
        G[(rbase + r) * GP + col] = (bf16_t)(s * p);
      }
    }
  }
  __syncthreads();
  // in-chunk cumsum over 128 rows; 4 threads per column (two-pass prefix)
  {
    int col = tid & 63;
    int q = tid >> 6;                 // quarter: rows q*32 .. q*32+31
    float lsum = 0.f;
#pragma unroll 8
    for (int r = 0; r < 32; ++r)
      lsum += (float)G[(q * 32 + r) * GP + col];
    tot[q][col] = lsum;
    __syncthreads();
    float run = 0.f;
#pragma unroll
    for (int qq = 0; qq < 3; ++qq)
      if (qq < q) run += tot[qq][col];
    int gc = n0 + col;                // global col = h*64 + d
    size_t obase = (size_t)(m0 + q * 32) * N + gc;
#pragma unroll 8
    for (int r = 0; r < 32; ++r) {
      run += (float)G[(q * 32 + r) * GP + col];
      lcm[obase + (size_t)r * N] = (bf16_t)run;
    }
    if (q == 3) {
      int bb = m0 >> 12;              // batch
      int ci = (m0 >> 7) & 31;        // chunk index
      csum[(((size_t)bb * Hn + (gc >> 6)) * NCn + ci) * 64 + (gc & 63)] = run;
    }
  }
}

// ---------------- exclusive carry cumsum over chunks + LN(D) --------------------
__global__ __launch_bounds__(64) void k_carry_ln(const float* __restrict__ csum,
                                                 float* __restrict__ ncar,
                                                 const float* __restrict__ g,
                                                 const float* __restrict__ be) {
  int bh = blockIdx.x;
  int d = threadIdx.x;
  float gd = g[d], bd = be[d];
  float run = 0.f;
  for (int ci = 0; ci < NCn; ++ci) {
    float v = run;  // exclusive prefix
    run += csum[((size_t)bh * NCn + ci) * 64 + d];
    float m = wsum64(v) * (1.f / 64.f);
    float dv = v - m;
    float var = wsum64(dv * dv) * (1.f / 64.f);
    ncar[((size_t)bh * NCn + ci) * 64 + d] = dv * rsqrtf(var + 1e-5f) * gd + bd;
  }
}

// ---------------- fused cards-LN + ho1 -> gelu -> ho2 per (b,h,chunk) -----------
// R7 LN fusion kept; x now staged via global_load_lds into linear swizzled LDS
// (full-line coalesced) instead of 16-row-scattered register fragments.
// Phase-1 LDS: Sx[128*64] (x, swizzled cols) + Sc[128*72] (cards, padded).
// Phase-2 LDS: same 34.8KB reused as h tile [128][136].
__global__ __launch_bounds__(256, 4) void k_ho_fused(
    const bf16_t* __restrict__ X, const bf16_t* __restrict__ lcm,
    const float* __restrict__ ncar, const float* __restrict__ cg,
    const float* __restrict__ cb, const bf16_t* __restrict__ W1t,
    const float* __restrict__ b1, const bf16_t* __restrict__ W2t,
    const float* __restrict__ b2, bf16_t* __restrict__ ho) {
  __shared__ __align__(16) bf16_t S[17408];  // 34.8KB
  bf16_t* Sx = S;            // [128][64] linear, source-swizzled
  bf16_t* Sc = S + 8192;     // [128] rows x stride 72
  int tid = threadIdx.x;
  int ci = blockIdx.x & 31, bh = blockIdx.x >> 5;
  int h = bh & 15, b = bh >> 4;
  int wave = tid >> 6, lane = tid & 63;
  int wm = wave >> 1, wn = wave & 1;
  int lr = lane & 15, lk = lane >> 4;
  size_t xrow0 = (size_t)(b * Tn + ci * CSn);

  // stage x -> Sx via gld16: 4 instrs/wave, 8 rows each, full 128B lines,
  // source col pre-swizzled so frag reads are conflict-free
  {
    const bf16_t* xb = X + xrow0 * Cn + h * Dn;
#pragma unroll
    for (int c = 0; c < 4; ++c) {
      int row = wave * 32 + c * 8 + (lane >> 3);
      int c16 = (lane & 7) ^ (row & 7);
      gld16(xb + (size_t)row * Cn + c16 * 8, Sx + (wave * 32 + c * 8) * 64);
    }
  }

  // cards: in-register LN (two-pass variance) -> Sc, 8 lanes/row x 8 elems
  {
    int lg = lane >> 3;   // row offset within an 8-row batch
    int le = lane & 7;    // which 8-elem slice of d
    int d0 = le * 8;
    const float* np = ncar + ((size_t)bh * NCn + ci) * 64 + d0;
    float ncv[8], ggv[8], bbv[8];
#pragma unroll
    for (int e = 0; e < 8; ++e) {
      ncv[e] = np[e];
      ggv[e] = cg[d0 + e];
      bbv[e] = cb[d0 + e];
    }
#pragma unroll
    for (int it = 0; it < 4; ++it) {
      int pr = wave * 32 + it * 8 + lg;   // 0..127
      float v[8];
      if (pr > 0) {
        bf16x8 lv = *reinterpret_cast<const bf16x8*>(
            lcm + (xrow0 + pr - 1) * Cn + h * Dn + d0);
#pragma unroll
        for (int e = 0; e < 8; ++e) v[e] = (float)lv[e] + ncv[e];
      } else {
#pragma unroll
        for (int e = 0; e < 8; ++e) v[e] = ncv[e];
      }
      float s = 0.f;
#pragma unroll
      for (int e = 0; e < 8; ++e) s += v[e];
      s += __shfl_xor(s, 1, 64);
      s += __shfl_xor(s, 2, 64);
      s += __shfl_xor(s, 4, 64);
      float mean = s * (1.f / 64.f);
      float q = 0.f;
#pragma unroll
      for (int e = 0; e < 8; ++e) { float dv = v[e] - mean; q += dv * dv; }
      q += __shfl_xor(q, 1, 64);
      q += __shfl_xor(q, 2, 64);
      q += __shfl_xor(q, 4, 64);
      float rs = rsqrtf(q * (1.f / 64.f) + 1e-5f);
      bf16x8 o;
#pragma unroll
      for (int e = 0; e < 8; ++e)
        o[e] = (bf16_t)((v[e] - mean) * rs * ggv[e] + bbv[e]);
      *reinterpret_cast<bf16x8*>(&Sc[pr * 72 + d0]) = o;
    }
  }
  __syncthreads();
  f32x4 acc[4][4] = {};
#pragma unroll
  for (int ks = 0; ks < 4; ++ks) {
    bf16x8 af[4], bfr[4];
#pragma unroll
    for (int i = 0; i < 4; ++i) {
      int row = wm * 64 + i * 16 + lr;
      if (ks < 2) {
        int c16 = (ks * 4 + lk) ^ (row & 7);
        af[i] = *reinterpret_cast<const bf16x8*>(&Sx[row * 64 + c16 * 8]);
      } else {
        af[i] = *reinterpret_cast<const bf16x8*>(&Sc[row * 72 + (ks - 2) * 32 + lk * 8]);
      }
    }
#pragma unroll
    for (int j = 0; j < 4; ++j)
      bfr[j] = *reinterpret_cast<const bf16x8*>(
          W1t + (size_t)(wn * 64 + j * 16 + lr) * 128 + ks * 32 + lk * 8);
#pragma unroll
    for (int i = 0; i < 4; ++i)
#pragma unroll
      for (int j = 0; j < 4; ++j)
        acc[i][j] = __builtin_amdgcn_mfma_f32_16x16x32_bf16(af[i], bfr[j], acc[i][j], 0, 0, 0);
  }
  __syncthreads();
  // h = gelu(acc + b1) into S as [128][136]
#pragma unroll
  for (int j = 0; j < 4; ++j) {
    int col = wn * 64 + j * 16 + lr;
    float bv = b1[col];
#pragma unroll
    for (int i = 0; i < 4; ++i) {
      int rbase = wm * 64 + i * 16 + lk * 4;
#pragma unroll
      for (int r = 0; r < 4; ++r)
        S[(rbase + r) * 136 + col] = (bf16_t)gelu_f(acc[i][j][r] + bv);
    }
  }
  __syncthreads();
  f32x4 acc2[2][4] = {};
#pragma unroll
  for (int ks = 0; ks < 4; ++ks) {
    bf16x8 af[2], bfr[4];
#pragma unroll
    for (int i = 0; i < 2; ++i)
      af[i] = *reinterpret_cast<const bf16x8*>(
          &S[(wave * 32 + i * 16 + lr) * 136 + ks * 32 + lk * 8]);
#pragma unroll
    for (int j = 0; j < 4; ++j)
      bfr[j] = *reinterpret_cast<const bf16x8*>(
          W2t + (size_t)(j * 16 + lr) * 128 + ks * 32 + lk * 8);
#pragma unroll
    for (int i = 0; i < 2; ++i)
#pragma unroll
      for (int j = 0; j < 4; ++j)
        acc2[i][j] = __builtin_amdgcn_mfma_f32_16x16x32_bf16(af[i], bfr[j], acc2[i][j], 0, 0, 0);
  }
#pragma unroll
  for (int j = 0; j < 4; ++j) {
    int dd = j * 16 + lr;
    float bv = b2[dd];
#pragma unroll
    for (int i = 0; i < 2; ++i) {
      int pbase = wave * 32 + i * 16 + lk * 4;
#pragma unroll
      for (int r = 0; r < 4; ++r)
        ho[(xrow0 + pbase + r) * Cn + h * Dn + dd] = (bf16_t)(acc2[i][j][r] + bv);
    }
  }
}

// ---------------- proj GEMM: 128x128 tile, BK=64, swizzled staging --------------
__global__ __launch_bounds__(256, 2) void k_gemm_bt(
    const bf16_t* __restrict__ A, const bf16_t* __restrict__ Wt,
    const float* __restrict__ bias, bf16_t* __restrict__ out) {
  constexpr int K = Cn, N = Cn;
  __shared__ __align__(16) bf16_t L[32768];  // A[2][8192] B[2][8192]
  int tid = threadIdx.x;
  int Lb = blockIdx.x + 8 * blockIdx.y;
  int xcd = Lb & 7, jj = Lb >> 3;
  int nb = jj & 7, mb = xcd + 8 * (jj >> 3);
  int m0 = mb * 128, n0 = nb * 128;
  int wave = tid >> 6, lane = tid & 63;
  int wm = wave >> 1, wn = wave & 1;
  int lr = lane & 15, lk = lane >> 4;
  int sr = lane >> 3;
  int sc = (lane & 7) ^ sr;
  f32x4 acc[4][4] = {};
  const bf16_t* Ab = A + (size_t)m0 * K;
  const bf16_t* Wb = Wt + (size_t)n0 * K;
  bf16_t* LA = L;          // 2 x 8192
  bf16_t* LB = L + 16384;  // 2 x 8192

#define STAGE2(buf, kt)                                                    \
  {                                                                        \
    _Pragma("unroll")                                                      \
    for (int c = 0; c < 4; ++c) {                                          \
      int r8 = wave * 32 + c * 8;                                          \
      size_t go = (size_t)(r8 + sr) * K + (kt) * 64 + sc * 8;              \
      gld16(Ab + go, LA + (buf) * 8192 + r8 * 64);                         \
      gld16(Wb + go, LB + (buf) * 8192 + r8 * 64);                         \
    }                                                                      \
  }

  STAGE2(0, 0);
  __syncthreads();
  int cur = 0;
  for (int kt = 0; kt < 16; ++kt) {
    if (kt < 15) STAGE2(cur ^ 1, kt + 1);
#pragma unroll
    for (int ks = 0; ks < 2; ++ks) {
      int sl = ((ks * 4 + lk) ^ (lr & 7)) * 8;
      bf16x8 af[4], bfr[4];
#pragma unroll
      for (int i = 0; i < 4; ++i)
        af[i] = *reinterpret_cast<const bf16x8*>(
            &LA[cur * 8192 + (wm * 64 + i * 16 + lr) * 64 + sl]);
#pragma unroll
      for (int j = 0; j < 4; ++j)
        bfr[j] = *reinterpret_cast<const bf16x8*>(
            &LB[cur * 8192 + (wn * 64 + j * 16 + lr) * 64 + sl]);
#pragma unroll
      for (int i = 0; i < 4; ++i)
#pragma unroll
        for (int j = 0; j < 4; ++j)
          acc[i][j] = __builtin_amdgcn_mfma_f32_16x16x32_bf16(af[i], bfr[j], acc[i][j], 0, 0, 0);
    }
    __syncthreads();
    cur ^= 1;
  }
#undef STAGE2
#pragma unroll
  for (int j = 0; j < 4; ++j) {
    int col = n0 + wn * 64 + j * 16 + lr;
    float bv = bias[col];
#pragma unroll
    for (int i = 0; i < 4; ++i) {
      int rbase = m0 + wm * 64 + i * 16 + lk * 4;
#pragma unroll
      for (int r = 0; r < 4; ++r)
        out[(size_t)(rbase + r) * N + col] = (bf16_t)(acc[i][j][r] + bv);
    }
  }
}

// ---------------- final LN over C + residual (bf16 pre + bf16 x, fp32 out) ------
__global__ __launch_bounds__(256) void k_ln_residual(
    const bf16_t* __restrict__ pre, const bf16_t* __restrict__ Xb,
    const float* __restrict__ g, const float* __restrict__ be,
    float* __restrict__ out) {
  int row = blockIdx.x, t = threadIdx.x;
  size_t base = (size_t)row * Cn + t * 4;
  bf16x4 pv4 = *reinterpret_cast<const bf16x4*>(pre + base);
  float v0 = (float)pv4[0], v1 = (float)pv4[1], v2 = (float)pv4[2], v3 = (float)pv4[3];
  float s = v0 + v1 + v2 + v3;
  float q = v0 * v0 + v1 * v1 + v2 * v2 + v3 * v3;
  s = wsum64(s);
  q = wsum64(q);
  __shared__ float red[8];
  int wv = t >> 6, ln = t & 63;
  if (ln == 0) { red[wv] = s; red[4 + wv] = q; }
  __syncthreads();
  float tot = red[0] + red[1] + red[2] + red[3];
  float totq = red[4] + red[5] + red[6] + red[7];
  float mean = tot * (1.f / 1024.f);
  float var = totq * (1.f / 1024.f) - mean * mean;
  float rs = rsqrtf(fmaxf(var, 0.f) + 1e-5f);
  bf16x4 xv4 = *reinterpret_cast<const bf16x4*>(Xb + base);
  float4 gv = *reinterpret_cast<const float4*>(g + t * 4);
  float4 bv = *reinterpret_cast<const float4*>(be + t * 4);
  float4 o;
  o.x = (v0 - mean) * rs * gv.x + bv.x + (float)xv4[0];
  o.y = (v1 - mean) * rs * gv.y + bv.y + (float)xv4[1];
  o.z = (v2 - mean) * rs * gv.z + bv.z + (float)xv4[2];
  o.w = (v3 - mean) * rs * gv.w + bv.w + (float)xv4[3];
  *reinterpret_cast<float4*>(out + base) = o;
}

extern "C" void kernel_launch(void* const* d_in, const int* in_sizes, int n_in,
                              void* d_out, int out_size, void* d_ws, size_t ws_size,
                              hipStream_t stream) {
  const float* x       = (const float*)d_in[0];
  const float* mark_W  = (const float*)d_in[1];
  const float* mark_b  = (const float*)d_in[2];
  const float* gate_W  = (const float*)d_in[3];
  const float* gate_b  = (const float*)d_in[4];
  const float* carry_g = (const float*)d_in[5];
  const float* carry_b = (const float*)d_in[6];
  const float* card_g  = (const float*)d_in[7];
  const float* card_b  = (const float*)d_in[8];
  const float* ho1_W   = (const float*)d_in[9];
  const float* ho1_b   = (const float*)d_in[10];
  const float* ho2_W   = (const float*)d_in[11];
  const float* ho2_b   = (const float*)d_in[12];
  const float* proj_W  = (const float*)d_in[13];
  const float* proj_b  = (const float*)d_in[14];
  const float* ln_g    = (const float*)d_in[15];
  const float* ln_b    = (const float*)d_in[16];
  float* out = (float*)d_out;

  char* ws = (char*)d_ws;
  bf16_t* xbf    = (bf16_t*)(ws + 0);          // live until ln_residual
  bf16_t* gm     = (bf16_t*)(ws + 33554432);   // lcm (cumsum'd gm)
  bf16_t* outpre = (bf16_t*)(ws + 67108864);   // proj output (bf16)
  bf16_t* hobuf  = (bf16_t*)(ws + 100663296);
  float*  csum   = (float*)(ws + 134217728);
  float*  ncar   = (float*)(ws + 134742016);
  bf16_t* wtm    = (bf16_t*)(ws + 135266304);
  bf16_t* wtg    = (bf16_t*)(ws + 137363456);
  bf16_t* wtp    = (bf16_t*)(ws + 139460608);
  bf16_t* wt1    = (bf16_t*)(ws + 141557760);
  bf16_t* wt2    = (bf16_t*)(ws + 141590528);

  k_xbf<<<8192, 256, 0, stream>>>(x, xbf);
  k_transpose<<<dim3(16, 16), 256, 0, stream>>>(mark_W, wtm, 1024, 1024);
  k_transpose<<<dim3(16, 16), 256, 0, stream>>>(gate_W, wtg, 1024, 1024);
  k_transpose<<<dim3(16, 16), 256, 0, stream>>>(proj_W, wtp, 1024, 1024);
  k_transpose<<<dim3(2, 2),   256, 0, stream>>>(ho1_W, wt1, 128, 128);
  k_transpose<<<dim3(1, 2),   256, 0, stream>>>(ho2_W, wt2, 128, 64);

  k_dualgemm_gm<<<2048, 256, 0, stream>>>(xbf, wtm, wtg, mark_b, gate_b, gm, csum);
  k_carry_ln<<<64, 64, 0, stream>>>(csum, ncar, carry_g, carry_b);
  k_ho_fused<<<2048, 256, 0, stream>>>(xbf, gm, ncar, card_g, card_b,
                                       wt1, ho1_b, wt2, ho2_b, hobuf);
  k_gemm_bt<<<dim3(8, 128), 256, 0, stream>>>(hobuf, wtp, proj_b, outpre);
  k_ln_residual<<<16384, 256, 0, stream>>>(outpre, xbf, ln_g, ln_b, out);
}